// Round 6
// baseline (1035.903 us; speedup 1.0000x reference)
//
#include <hip/hip_runtime.h>
#include <hip/hip_bf16.h>

// CrossAttention: b=4, n=1024, qs=256, heads=8, dim_head=64, bottleneck=40.
// Attention = full 8192x8192 softmax-attention per batch over D=64.
//
// R6: occupancy/latency round.
//  - qkv split per projection: 768 blocks (3/CU) instead of 256 (1/CU).
//  - attn: 512-thread blocks (8 waves, kv split 8-way). Same 2 blocks/CU ->
//    identical L2 footprint (4MB/CU), but 16 waves/CU to overlap the three
//    balanced pipes (MFMA 621 / VALU ~360 / L2 ~585 cyc per pair-round).
//    Epilogue reduces O in per-mt chunks to keep LDS at 36.9 KB.
//  - out_kernel: 1024 blocks (8 rows x 128 cols), 4/CU.
//
// Workspace: Q 4MB | K_sw 4MB | V_sw 4MB (bf16) | O 8MB (fp32) = 20MB.

#define B_    4
#define H_    8
#define NSEQ  1024
#define SEQ   8192        // H_*NSEQ
#define DH    64
#define QS    256
#define INNER 512
#define QSCALE 0.18033688011112042f   // (1/sqrt(64)) * log2(e)

#define KVSW_BATCH 524288             // elems per batch in K_sw / V_sw

typedef __bf16 bf16x8 __attribute__((ext_vector_type(8)));
typedef float floatx4 __attribute__((ext_vector_type(4)));

// ---------------- kernel 1: QKV projections + fragment-order swizzle ----------------
// grid 768: blk = p*256 + b*64 + nblk. One projection per block, 16 x-rows.
//   Qg  [b][h*1024+n][64]                       (row-major)
//   KSg [b][t16=kv>>4][ks=d>>5][lane][j]   lane=((d>>3)&3)*16 + (kv&15), j=d&7
//   VSg [b][p=kv>>5][dnt=d>>4][lane][j]    lane=((kv>>2)&3)*16 + (d&15), j=((kv>>4)&1)*4+(kv&3)
__global__ __launch_bounds__(256, 3) void qkv_kernel(
    const float* __restrict__ x,
    const float* __restrict__ wq1, const float* __restrict__ wq2,
    const float* __restrict__ wk1, const float* __restrict__ wk2,
    const float* __restrict__ wv1, const float* __restrict__ wv2,
    __hip_bfloat16* __restrict__ Qg, __hip_bfloat16* __restrict__ KSg,
    __hip_bfloat16* __restrict__ VSg)
{
  const int tid  = threadIdx.x;
  const int p    = blockIdx.x >> 8;          // 0=Q 1=K 2=V
  const int rem  = blockIdx.x & 255;
  const int b    = rem >> 6;
  const int nblk = rem & 63;
  const int n0   = nblk << 4;

  __shared__ __align__(16) float xs[16][260];            // pad 260: break row aliasing
  __shared__ __align__(16) float tb[16][40];
  __shared__ __align__(16) __hip_bfloat16 ob[10240];     // p<2: [16][520]; p==2: [512][20]

  const float* w1 = (p == 0) ? wq1 : (p == 1) ? wk1 : wv1;
  const float* w2 = (p == 0) ? wq2 : (p == 1) ? wk2 : wv2;

  for (int i = tid; i < 16 * 256; i += 256) {
    const int r = i >> 8, c = i & 255;
    xs[r][c] = x[((size_t)b * NSEQ + n0 + r) * QS + c];
  }
  __syncthreads();

  // stage 1: bottleneck (16 rows x 10 col-quads = 160 tasks)
  if (tid < 160) {
    const int r  = tid / 10;
    const int bn = (tid - r * 10) * 4;
    float a0 = 0.f, a1 = 0.f, a2 = 0.f, a3 = 0.f;
    for (int c4 = 0; c4 < 64; ++c4) {
      const float4 xv = *(const float4*)(&xs[r][c4 * 4]);
      const float4 wa = *(const float4*)(w1 + (c4 * 4 + 0) * 40 + bn);
      const float4 wb = *(const float4*)(w1 + (c4 * 4 + 1) * 40 + bn);
      const float4 wc = *(const float4*)(w1 + (c4 * 4 + 2) * 40 + bn);
      const float4 wd = *(const float4*)(w1 + (c4 * 4 + 3) * 40 + bn);
      a0 += xv.x * wa.x + xv.y * wb.x + xv.z * wc.x + xv.w * wd.x;
      a1 += xv.x * wa.y + xv.y * wb.y + xv.z * wc.y + xv.w * wd.y;
      a2 += xv.x * wa.z + xv.y * wb.z + xv.z * wc.z + xv.w * wd.z;
      a3 += xv.x * wa.w + xv.y * wb.w + xv.z * wc.w + xv.w * wd.w;
    }
    if (p == 1) {   // SiLU on K bottleneck
      a0 = a0 / (1.f + __expf(-a0));
      a1 = a1 / (1.f + __expf(-a1));
      a2 = a2 / (1.f + __expf(-a2));
      a3 = a3 / (1.f + __expf(-a3));
    }
    tb[r][bn + 0] = a0; tb[r][bn + 1] = a1;
    tb[r][bn + 2] = a2; tb[r][bn + 3] = a3;
  }
  __syncthreads();

  // stage 2: project to 512 (16 rows x 128 col-quads = 512 tasks, 2 passes)
  const float scale = (p == 0) ? QSCALE : 1.0f;
  #pragma unroll
  for (int pass = 0; pass < 2; ++pass) {
    const int task = tid + pass * 256;
    const int cq = task & 127;
    const int rq = (task >> 7) & 3;
    const int c  = cq * 4, r0 = rq * 4;
    float acc[4][4];
    #pragma unroll
    for (int i = 0; i < 4; ++i)
      #pragma unroll
      for (int j = 0; j < 4; ++j) acc[i][j] = 0.f;

    for (int jb = 0; jb < 10; ++jb) {
      const float4 w0 = *(const float4*)(w2 + (jb * 4 + 0) * INNER + c);
      const float4 w1r = *(const float4*)(w2 + (jb * 4 + 1) * INNER + c);
      const float4 w2r = *(const float4*)(w2 + (jb * 4 + 2) * INNER + c);
      const float4 w3 = *(const float4*)(w2 + (jb * 4 + 3) * INNER + c);
      #pragma unroll
      for (int ri = 0; ri < 4; ++ri) {
        const float4 tv = *(const float4*)(&tb[r0 + ri][jb * 4]);
        acc[ri][0] += tv.x * w0.x + tv.y * w1r.x + tv.z * w2r.x + tv.w * w3.x;
        acc[ri][1] += tv.x * w0.y + tv.y * w1r.y + tv.z * w2r.y + tv.w * w3.y;
        acc[ri][2] += tv.x * w0.z + tv.y * w1r.z + tv.z * w2r.z + tv.w * w3.z;
        acc[ri][3] += tv.x * w0.w + tv.y * w1r.w + tv.z * w2r.w + tv.w * w3.w;
      }
    }
    #pragma unroll
    for (int ri = 0; ri < 4; ++ri)
      #pragma unroll
      for (int ci = 0; ci < 4; ++ci) {
        const int cc = c + ci;
        const float v = acc[ri][ci] * scale;
        if (p < 2) ob[(r0 + ri) * 520 + cc] = __float2bfloat16(v);   // row-major
        else       ob[cc * 20 + (r0 + ri)]  = __float2bfloat16(v);   // transposed
      }
  }
  __syncthreads();

  // swizzled write pass (one per projection)
  if (p == 0) {
    // Q: row-major, coalesced
    const int row = tid >> 4;
    const int col = (tid & 15) * 32;
    const int h = col >> 6, d0 = col & 63;
    __hip_bfloat16* dst = Qg + ((size_t)b * SEQ + h * NSEQ + n0 + row) * DH + d0;
    #pragma unroll
    for (int i = 0; i < 4; ++i)
      *(float4*)(dst + i * 8) = *(const float4*)(&ob[row * 520 + col + i * 8]);
  } else if (p == 1) {
    // K_sw: fragment order, 16B chunks
    #pragma unroll
    for (int cc4 = 0; cc4 < 4; ++cc4) {
      const int c    = tid + cc4 * 256;          // [0,1024)
      const int h    = c >> 7;
      const int ks   = (c >> 6) & 1;
      const int lane = c & 63;
      const int lrow = lane & 15, quad = lane >> 4;
      const int t    = h * 64 + nblk;
      const size_t dst = (size_t)b * KVSW_BATCH + ((size_t)(t * 2 + ks) * 64 + lane) * 8;
      *(float4*)(KSg + dst) = *(const float4*)(&ob[lrow * 520 + h * 64 + ks * 32 + quad * 8]);
    }
  } else {
    // V_sw: fragment order, 8B chunks
    const int st = nblk & 1;
    #pragma unroll
    for (int cc8 = 0; cc8 < 8; ++cc8) {
      const int c    = tid + cc8 * 256;          // [0,2048)
      const int h    = c >> 8;
      const int dnt  = (c >> 6) & 3;
      const int lane = c & 63;
      const int lrow = lane & 15, quad = lane >> 4;
      const int pp   = h * 32 + (nblk >> 1);
      const size_t dst = (size_t)b * KVSW_BATCH + ((size_t)(pp * 4 + dnt) * 64 + lane) * 8 + st * 4;
      *(uint2*)(VSg + dst) = *(const uint2*)(&ob[(h * 64 + dnt * 16 + lrow) * 20 + quad * 4]);
    }
  }
}

// ---------------- kernel 2: attention, 8-wave blocks, zero-barrier main loop ----------------
// grid 512 1-D (XCD-swizzled: one batch per XCD pair-of-L2s), 512 threads = 8 waves.
// Each wave: the block's 64 q-rows x its private 1024-kv range (32 pairs of 32 kv).
struct PairBuf {
  bf16x8 k[2][2];   // [strip][k-span]
  bf16x8 v[4];      // [d-tile] (both strips packed, k-relabeled)
};

__global__ __launch_bounds__(512, 4) void attn_kernel(
    const __hip_bfloat16* __restrict__ Qg,
    const __hip_bfloat16* __restrict__ KSg,
    const __hip_bfloat16* __restrict__ VSg,
    float* __restrict__ Og)
{
  __shared__ float Osh[8][16][68];     // per-mt chunked partial-O reduction
  __shared__ float psums[8][64];

  const int tid  = threadIdx.x;
  const int wave = tid >> 6;
  const int lane = tid & 63;
  const int lrow = lane & 15;
  const int quad = lane >> 4;

  const int xcd   = blockIdx.x & 7;
  const int idx   = blockIdx.x >> 3;
  const int b     = xcd >> 1;
  const int qtile = (xcd & 1) * 64 + idx;
  const int qbase = qtile * 64;

  const __hip_bfloat16* Qb  = Qg + ((size_t)b * SEQ + qbase) * DH;
  const __hip_bfloat16* kp0 = KSg + (size_t)b * KVSW_BATCH + (size_t)wave * 65536 + lane * 8;
  const __hip_bfloat16* vp0 = VSg + (size_t)b * KVSW_BATCH + (size_t)wave * 65536 + lane * 8;

  // Q fragments in registers for the whole loop (same 64 q rows for all waves)
  bf16x8 qf[4][2];
  #pragma unroll
  for (int mt = 0; mt < 4; ++mt)
    #pragma unroll
    for (int s = 0; s < 2; ++s)
      qf[mt][s] = *(const bf16x8*)(Qb + (mt * 16 + lrow) * DH + s * 32 + quad * 8);

  floatx4 oacc[4][4];   // [mt][dnt]: O[q=mt*16+quad*4+r][d=dnt*16+lrow]
  #pragma unroll
  for (int mt = 0; mt < 4; ++mt)
    #pragma unroll
    for (int dnt = 0; dnt < 4; ++dnt)
      oacc[mt][dnt] = (floatx4){0.f, 0.f, 0.f, 0.f};
  float psum[4] = {0.f, 0.f, 0.f, 0.f};   // per-lane partials, q = mt*16+lrow

  auto load_pair = [&](PairBuf& pb, int pair) {
    const __hip_bfloat16* kp = kp0 + pair * 2048;
    pb.k[0][0] = *(const bf16x8*)(kp);
    pb.k[0][1] = *(const bf16x8*)(kp + 512);
    pb.k[1][0] = *(const bf16x8*)(kp + 1024);
    pb.k[1][1] = *(const bf16x8*)(kp + 1536);
    const __hip_bfloat16* vp = vp0 + pair * 2048;
    #pragma unroll
    for (int dnt = 0; dnt < 4; ++dnt)
      pb.v[dnt] = *(const bf16x8*)(vp + dnt * 512);
  };

  auto compute_pair = [&](const PairBuf& pb) {
    bf16x8 pA[4];
    #pragma unroll
    for (int mt = 0; mt < 4; ++mt) {
      floatx4 s0 = (floatx4){0.f, 0.f, 0.f, 0.f};
      floatx4 s1 = (floatx4){0.f, 0.f, 0.f, 0.f};
      s0 = __builtin_amdgcn_mfma_f32_16x16x32_bf16(pb.k[0][0], qf[mt][0], s0, 0, 0, 0);
      s0 = __builtin_amdgcn_mfma_f32_16x16x32_bf16(pb.k[0][1], qf[mt][1], s0, 0, 0, 0);
      s1 = __builtin_amdgcn_mfma_f32_16x16x32_bf16(pb.k[1][0], qf[mt][0], s1, 0, 0, 0);
      s1 = __builtin_amdgcn_mfma_f32_16x16x32_bf16(pb.k[1][1], qf[mt][1], s1, 0, 0, 0);
      float p[8];
      #pragma unroll
      for (int r = 0; r < 4; ++r) {
        p[r]     = __builtin_amdgcn_exp2f(s0[r]);
        p[4 + r] = __builtin_amdgcn_exp2f(s1[r]);
      }
      psum[mt] += ((p[0] + p[1]) + (p[2] + p[3])) + ((p[4] + p[5]) + (p[6] + p[7]));
      bf16x8 pa;
      #pragma unroll
      for (int j = 0; j < 8; ++j) pa[j] = (__bf16)p[j];
      pA[mt] = pa;
    }
    #pragma unroll
    for (int dnt = 0; dnt < 4; ++dnt)
      #pragma unroll
      for (int mt = 0; mt < 4; ++mt)
        oacc[mt][dnt] = __builtin_amdgcn_mfma_f32_16x16x32_bf16(pA[mt], pb.v[dnt], oacc[mt][dnt], 0, 0, 0);
  };

  PairBuf buf0, buf1;
  load_pair(buf0, 0);
  #pragma unroll 2
  for (int pair = 0; pair < 32; ++pair) {
    PairBuf& cur = (pair & 1) ? buf1 : buf0;
    PairBuf& nxt = (pair & 1) ? buf0 : buf1;
    const int pn = (pair < 31) ? pair + 1 : 31;
    load_pair(nxt, pn);
    compute_pair(cur);
  }

  // psum: reduce over quads (lane's q = mt*16+lrow), publish per-wave partials
  #pragma unroll
  for (int mt = 0; mt < 4; ++mt) {
    float s = psum[mt];
    s += __shfl_xor(s, 16, 64);
    s += __shfl_xor(s, 32, 64);
    psum[mt] = s;
  }
  if (quad == 0) {
    #pragma unroll
    for (int mt = 0; mt < 4; ++mt)
      psums[wave][mt * 16 + lrow] = psum[mt];
  }

  // chunked cross-wave O reduction: one 16-q tile (mt) at a time
  #pragma unroll
  for (int mt = 0; mt < 4; ++mt) {
    #pragma unroll
    for (int dnt = 0; dnt < 4; ++dnt)
      #pragma unroll
      for (int r = 0; r < 4; ++r)
        Osh[wave][quad * 4 + r][dnt * 16 + lrow] = oacc[mt][dnt][r];
    __syncthreads();   // Osh (and, first iter, psums) visible

    {
      const int q16 = tid >> 5;            // [0,16)
      const int d0  = (tid & 31) * 2;      // [0,64) step 2
      float tot = 0.f;
      #pragma unroll
      for (int w = 0; w < 8; ++w) tot += psums[w][mt * 16 + q16];
      const float inv = 1.0f / tot;
      float o0 = 0.f, o1 = 0.f;
      #pragma unroll
      for (int w = 0; w < 8; ++w) {
        o0 += Osh[w][q16][d0];
        o1 += Osh[w][q16][d0 + 1];
      }
      const size_t row = (size_t)b * SEQ + qbase + mt * 16 + q16;
      float2 res; res.x = o0 * inv; res.y = o1 * inv;
      *(float2*)(Og + row * DH + d0) = res;
    }
    __syncthreads();   // reduction reads done before Osh overwrite
  }
}

// ---------------- kernel 3: out = O @ wo + bo ----------------
// grid 1024: blk = b*256 + nb*2 + cs. Block = 8 rows x 128 out-cols.
__global__ __launch_bounds__(256, 4) void out_kernel(
    const float* __restrict__ Og, const float* __restrict__ wo,
    const float* __restrict__ bo, float* __restrict__ out)
{
  const int tid = threadIdx.x;
  const int cs  = blockIdx.x & 1;
  const int nb  = (blockIdx.x >> 1) & 127;
  const int b   = blockIdx.x >> 8;
  const int n0  = nb * 8;

  __shared__ __align__(16) float os[8][512];   // gathered (n, h*64+d) rows
  for (int i = tid; i < 8 * 512; i += 256) {
    const int r = i >> 9, cc = i & 511;
    os[r][cc] = Og[((size_t)b * SEQ + (cc >> 6) * NSEQ + n0 + r) * DH + (cc & 63)];
  }
  __syncthreads();

  const int rh = tid >> 5;                  // row [0,8)
  const int o  = cs * 128 + (tid & 31) * 4; // out col
  float a0 = 0.f, a1 = 0.f, a2 = 0.f, a3 = 0.f;

  for (int jb = 0; jb < 128; ++jb) {
    const float4 ov = *(const float4*)(&os[rh][jb * 4]);
    const float4 w0 = *(const float4*)(wo + (jb * 4 + 0) * QS + o);
    const float4 w1 = *(const float4*)(wo + (jb * 4 + 1) * QS + o);
    const float4 w2 = *(const float4*)(wo + (jb * 4 + 2) * QS + o);
    const float4 w3 = *(const float4*)(wo + (jb * 4 + 3) * QS + o);
    a0 += ov.x * w0.x + ov.y * w1.x + ov.z * w2.x + ov.w * w3.x;
    a1 += ov.x * w0.y + ov.y * w1.y + ov.z * w2.y + ov.w * w3.y;
    a2 += ov.x * w0.z + ov.y * w1.z + ov.z * w2.z + ov.w * w3.z;
    a3 += ov.x * w0.w + ov.y * w1.w + ov.z * w2.w + ov.w * w3.w;
  }

  const float4 bv = *(const float4*)(bo + o);
  float4 res;
  res.x = a0 + bv.x; res.y = a1 + bv.y; res.z = a2 + bv.z; res.w = a3 + bv.w;
  *(float4*)(out + ((size_t)b * NSEQ + n0 + rh) * QS + o) = res;
}

extern "C" void kernel_launch(void* const* d_in, const int* in_sizes, int n_in,
                              void* d_out, int out_size, void* d_ws, size_t ws_size,
                              hipStream_t stream) {
  const float* x   = (const float*)d_in[0];
  const float* wq1 = (const float*)d_in[1];
  const float* wq2 = (const float*)d_in[2];
  const float* wk1 = (const float*)d_in[3];
  const float* wk2 = (const float*)d_in[4];
  const float* wv1 = (const float*)d_in[5];
  const float* wv2 = (const float*)d_in[6];
  const float* wo  = (const float*)d_in[7];
  const float* bo  = (const float*)d_in[8];
  float* out = (float*)d_out;

  __hip_bfloat16* Qg  = (__hip_bfloat16*)d_ws;
  __hip_bfloat16* KSg = Qg + (size_t)B_ * SEQ * DH;
  __hip_bfloat16* VSg = KSg + (size_t)B_ * KVSW_BATCH;
  float*          Og  = (float*)(VSg + (size_t)B_ * KVSW_BATCH);

  qkv_kernel<<<768, 256, 0, stream>>>(x, wq1, wq2, wk1, wk2, wv1, wv2, Qg, KSg, VSg);
  attn_kernel<<<512, 512, 0, stream>>>(Qg, KSg, VSg, Og);
  out_kernel<<<1024, 256, 0, stream>>>(Og, wo, bo, out);
}

// Round 7
// 989.848 us; speedup vs baseline: 1.0465x; 1.0465x over previous
//
#include <hip/hip_runtime.h>
#include <hip/hip_bf16.h>

// CrossAttention: b=4, n=1024, qs=256, heads=8, dim_head=64, bottleneck=40.
// Attention = full 8192x8192 softmax-attention per batch over D=64.
//
// R7: R6's 8-wave block spilled (VGPR cap 64 vs ~170 need -> 2.6GB scratch
// traffic). Revert to R5's 4-wave/120-VGPR shape; reach 16 waves/CU by
// splitting kv across 2 blocks (grid 1024, launch_bounds(256,4) -> cap 128).
// Blocks emit partial O + partial denom; out_kernel merges+normalizes in its
// gather. Per-mt fused QK->exp2->PV shortens live ranges (~12 VGPRs saved).
//
// Workspace: Q 4MB | K_sw 4MB | V_sw 4MB | Opart 2x8MB | psum 2x128KB ~ 28.3MB.

#define B_    4
#define H_    8
#define NSEQ  1024
#define SEQ   8192        // H_*NSEQ
#define DH    64
#define QS    256
#define INNER 512
#define QSCALE 0.18033688011112042f   // (1/sqrt(64)) * log2(e)

#define KVSW_BATCH 524288             // elems per batch in K_sw / V_sw

typedef __bf16 bf16x8 __attribute__((ext_vector_type(8)));
typedef float floatx4 __attribute__((ext_vector_type(4)));

// ---------------- kernel 1: QKV projections + fragment-order swizzle ----------------
// grid 768: blk = p*256 + b*64 + nblk. One projection per block, 16 x-rows.
__global__ __launch_bounds__(256, 3) void qkv_kernel(
    const float* __restrict__ x,
    const float* __restrict__ wq1, const float* __restrict__ wq2,
    const float* __restrict__ wk1, const float* __restrict__ wk2,
    const float* __restrict__ wv1, const float* __restrict__ wv2,
    __hip_bfloat16* __restrict__ Qg, __hip_bfloat16* __restrict__ KSg,
    __hip_bfloat16* __restrict__ VSg)
{
  const int tid  = threadIdx.x;
  const int p    = blockIdx.x >> 8;          // 0=Q 1=K 2=V
  const int rem  = blockIdx.x & 255;
  const int b    = rem >> 6;
  const int nblk = rem & 63;
  const int n0   = nblk << 4;

  __shared__ __align__(16) float xs[16][260];
  __shared__ __align__(16) float tb[16][40];
  __shared__ __align__(16) __hip_bfloat16 ob[10240];     // p<2: [16][520]; p==2: [512][20]

  const float* w1 = (p == 0) ? wq1 : (p == 1) ? wk1 : wv1;
  const float* w2 = (p == 0) ? wq2 : (p == 1) ? wk2 : wv2;

  for (int i = tid; i < 16 * 256; i += 256) {
    const int r = i >> 8, c = i & 255;
    xs[r][c] = x[((size_t)b * NSEQ + n0 + r) * QS + c];
  }
  __syncthreads();

  if (tid < 160) {
    const int r  = tid / 10;
    const int bn = (tid - r * 10) * 4;
    float a0 = 0.f, a1 = 0.f, a2 = 0.f, a3 = 0.f;
    for (int c4 = 0; c4 < 64; ++c4) {
      const float4 xv = *(const float4*)(&xs[r][c4 * 4]);
      const float4 wa = *(const float4*)(w1 + (c4 * 4 + 0) * 40 + bn);
      const float4 wb = *(const float4*)(w1 + (c4 * 4 + 1) * 40 + bn);
      const float4 wc = *(const float4*)(w1 + (c4 * 4 + 2) * 40 + bn);
      const float4 wd = *(const float4*)(w1 + (c4 * 4 + 3) * 40 + bn);
      a0 += xv.x * wa.x + xv.y * wb.x + xv.z * wc.x + xv.w * wd.x;
      a1 += xv.x * wa.y + xv.y * wb.y + xv.z * wc.y + xv.w * wd.y;
      a2 += xv.x * wa.z + xv.y * wb.z + xv.z * wc.z + xv.w * wd.z;
      a3 += xv.x * wa.w + xv.y * wb.w + xv.z * wc.w + xv.w * wd.w;
    }
    if (p == 1) {   // SiLU on K bottleneck
      a0 = a0 / (1.f + __expf(-a0));
      a1 = a1 / (1.f + __expf(-a1));
      a2 = a2 / (1.f + __expf(-a2));
      a3 = a3 / (1.f + __expf(-a3));
    }
    tb[r][bn + 0] = a0; tb[r][bn + 1] = a1;
    tb[r][bn + 2] = a2; tb[r][bn + 3] = a3;
  }
  __syncthreads();

  const float scale = (p == 0) ? QSCALE : 1.0f;
  #pragma unroll
  for (int pass = 0; pass < 2; ++pass) {
    const int task = tid + pass * 256;
    const int cq = task & 127;
    const int rq = (task >> 7) & 3;
    const int c  = cq * 4, r0 = rq * 4;
    float acc[4][4];
    #pragma unroll
    for (int i = 0; i < 4; ++i)
      #pragma unroll
      for (int j = 0; j < 4; ++j) acc[i][j] = 0.f;

    for (int jb = 0; jb < 10; ++jb) {
      const float4 w0 = *(const float4*)(w2 + (jb * 4 + 0) * INNER + c);
      const float4 w1r = *(const float4*)(w2 + (jb * 4 + 1) * INNER + c);
      const float4 w2r = *(const float4*)(w2 + (jb * 4 + 2) * INNER + c);
      const float4 w3 = *(const float4*)(w2 + (jb * 4 + 3) * INNER + c);
      #pragma unroll
      for (int ri = 0; ri < 4; ++ri) {
        const float4 tv = *(const float4*)(&tb[r0 + ri][jb * 4]);
        acc[ri][0] += tv.x * w0.x + tv.y * w1r.x + tv.z * w2r.x + tv.w * w3.x;
        acc[ri][1] += tv.x * w0.y + tv.y * w1r.y + tv.z * w2r.y + tv.w * w3.y;
        acc[ri][2] += tv.x * w0.z + tv.y * w1r.z + tv.z * w2r.z + tv.w * w3.z;
        acc[ri][3] += tv.x * w0.w + tv.y * w1r.w + tv.z * w2r.w + tv.w * w3.w;
      }
    }
    #pragma unroll
    for (int ri = 0; ri < 4; ++ri)
      #pragma unroll
      for (int ci = 0; ci < 4; ++ci) {
        const int cc = c + ci;
        const float v = acc[ri][ci] * scale;
        if (p < 2) ob[(r0 + ri) * 520 + cc] = __float2bfloat16(v);
        else       ob[cc * 20 + (r0 + ri)]  = __float2bfloat16(v);
      }
  }
  __syncthreads();

  if (p == 0) {
    const int row = tid >> 4;
    const int col = (tid & 15) * 32;
    const int h = col >> 6, d0 = col & 63;
    __hip_bfloat16* dst = Qg + ((size_t)b * SEQ + h * NSEQ + n0 + row) * DH + d0;
    #pragma unroll
    for (int i = 0; i < 4; ++i)
      *(float4*)(dst + i * 8) = *(const float4*)(&ob[row * 520 + col + i * 8]);
  } else if (p == 1) {
    #pragma unroll
    for (int cc4 = 0; cc4 < 4; ++cc4) {
      const int c    = tid + cc4 * 256;
      const int h    = c >> 7;
      const int ks   = (c >> 6) & 1;
      const int lane = c & 63;
      const int lrow = lane & 15, quad = lane >> 4;
      const int t    = h * 64 + nblk;
      const size_t dst = (size_t)b * KVSW_BATCH + ((size_t)(t * 2 + ks) * 64 + lane) * 8;
      *(float4*)(KSg + dst) = *(const float4*)(&ob[lrow * 520 + h * 64 + ks * 32 + quad * 8]);
    }
  } else {
    const int st = nblk & 1;
    #pragma unroll
    for (int cc8 = 0; cc8 < 8; ++cc8) {
      const int c    = tid + cc8 * 256;
      const int h    = c >> 8;
      const int dnt  = (c >> 6) & 3;
      const int lane = c & 63;
      const int lrow = lane & 15, quad = lane >> 4;
      const int pp   = h * 32 + (nblk >> 1);
      const size_t dst = (size_t)b * KVSW_BATCH + ((size_t)(pp * 4 + dnt) * 64 + lane) * 8 + st * 4;
      *(uint2*)(VSg + dst) = *(const uint2*)(&ob[(h * 64 + dnt * 16 + lrow) * 20 + quad * 4]);
    }
  }
}

// ---------------- kernel 2: attention, kv-split partial blocks ----------------
// grid 1024: xcd=blk&7 (b = xcd>>1), idx=blk>>3: half=idx&1, qt=idx>>1.
// Block = 4 waves x 64 q-rows x 4096 kv (each wave a private 1024-kv range).
// Emits partial O (fp32) and partial softmax denominator; no normalization.
struct PairBuf {
  bf16x8 k[2][2];   // [strip][k-span]
  bf16x8 v[4];      // [d-tile]
};

__global__ __launch_bounds__(256, 4) void attn_kernel(
    const __hip_bfloat16* __restrict__ Qg,
    const __hip_bfloat16* __restrict__ KSg,
    const __hip_bfloat16* __restrict__ VSg,
    float* __restrict__ OPg,       // [2][B_][SEQ][DH]
    float* __restrict__ PSg)       // [2][B_][SEQ]
{
  __shared__ float Osh[4][16][68];
  __shared__ float psums[4][64];

  const int tid  = threadIdx.x;
  const int wave = tid >> 6;
  const int lane = tid & 63;
  const int lrow = lane & 15;
  const int quad = lane >> 4;

  const int xcd   = blockIdx.x & 7;
  const int idx   = blockIdx.x >> 3;       // [0,128)
  const int b     = xcd >> 1;
  const int half  = idx & 1;
  const int qtile = (xcd & 1) * 64 + (idx >> 1);
  const int qbase = qtile * 64;

  const __hip_bfloat16* Qb  = Qg + ((size_t)b * SEQ + qbase) * DH;
  const __hip_bfloat16* kp0 = KSg + (size_t)b * KVSW_BATCH + half * 262144
                              + (size_t)wave * 65536 + lane * 8;
  const __hip_bfloat16* vp0 = VSg + (size_t)b * KVSW_BATCH + half * 262144
                              + (size_t)wave * 65536 + lane * 8;

  bf16x8 qf[4][2];
  #pragma unroll
  for (int mt = 0; mt < 4; ++mt)
    #pragma unroll
    for (int s = 0; s < 2; ++s)
      qf[mt][s] = *(const bf16x8*)(Qb + (mt * 16 + lrow) * DH + s * 32 + quad * 8);

  floatx4 oacc[4][4];   // [mt][dnt]
  #pragma unroll
  for (int mt = 0; mt < 4; ++mt)
    #pragma unroll
    for (int dnt = 0; dnt < 4; ++dnt)
      oacc[mt][dnt] = (floatx4){0.f, 0.f, 0.f, 0.f};
  float psum[4] = {0.f, 0.f, 0.f, 0.f};

  auto load_pair = [&](PairBuf& pb, int pair) {
    const __hip_bfloat16* kp = kp0 + pair * 2048;
    pb.k[0][0] = *(const bf16x8*)(kp);
    pb.k[0][1] = *(const bf16x8*)(kp + 512);
    pb.k[1][0] = *(const bf16x8*)(kp + 1024);
    pb.k[1][1] = *(const bf16x8*)(kp + 1536);
    const __hip_bfloat16* vp = vp0 + pair * 2048;
    #pragma unroll
    for (int dnt = 0; dnt < 4; ++dnt)
      pb.v[dnt] = *(const bf16x8*)(vp + dnt * 512);
  };

  // per-mt fused QK -> exp2 -> pack -> PV (one pA live at a time)
  auto compute_pair = [&](const PairBuf& pb) {
    #pragma unroll
    for (int mt = 0; mt < 4; ++mt) {
      floatx4 s0 = (floatx4){0.f, 0.f, 0.f, 0.f};
      floatx4 s1 = (floatx4){0.f, 0.f, 0.f, 0.f};
      s0 = __builtin_amdgcn_mfma_f32_16x16x32_bf16(pb.k[0][0], qf[mt][0], s0, 0, 0, 0);
      s0 = __builtin_amdgcn_mfma_f32_16x16x32_bf16(pb.k[0][1], qf[mt][1], s0, 0, 0, 0);
      s1 = __builtin_amdgcn_mfma_f32_16x16x32_bf16(pb.k[1][0], qf[mt][0], s1, 0, 0, 0);
      s1 = __builtin_amdgcn_mfma_f32_16x16x32_bf16(pb.k[1][1], qf[mt][1], s1, 0, 0, 0);
      float p[8];
      #pragma unroll
      for (int r = 0; r < 4; ++r) {
        p[r]     = __builtin_amdgcn_exp2f(s0[r]);
        p[4 + r] = __builtin_amdgcn_exp2f(s1[r]);
      }
      psum[mt] += ((p[0] + p[1]) + (p[2] + p[3])) + ((p[4] + p[5]) + (p[6] + p[7]));
      bf16x8 pa;
      #pragma unroll
      for (int j = 0; j < 8; ++j) pa[j] = (__bf16)p[j];
      #pragma unroll
      for (int dnt = 0; dnt < 4; ++dnt)
        oacc[mt][dnt] = __builtin_amdgcn_mfma_f32_16x16x32_bf16(pa, pb.v[dnt], oacc[mt][dnt], 0, 0, 0);
    }
  };

  PairBuf buf0, buf1;
  load_pair(buf0, 0);
  #pragma unroll 2
  for (int pair = 0; pair < 32; ++pair) {
    PairBuf& cur = (pair & 1) ? buf1 : buf0;
    PairBuf& nxt = (pair & 1) ? buf0 : buf1;
    const int pn = (pair < 31) ? pair + 1 : 31;
    load_pair(nxt, pn);
    compute_pair(cur);
  }

  // quad-reduce psum, publish per-wave partials
  #pragma unroll
  for (int mt = 0; mt < 4; ++mt) {
    float s = psum[mt];
    s += __shfl_xor(s, 16, 64);
    s += __shfl_xor(s, 32, 64);
    psum[mt] = s;
  }
  if (quad == 0) {
    #pragma unroll
    for (int mt = 0; mt < 4; ++mt)
      psums[wave][mt * 16 + lrow] = psum[mt];
  }

  const size_t opbase = ((size_t)half * B_ + b) * SEQ + qbase;

  // chunked cross-wave O reduction (per 16-q tile); partials, no normalize
  #pragma unroll
  for (int mt = 0; mt < 4; ++mt) {
    #pragma unroll
    for (int dnt = 0; dnt < 4; ++dnt)
      #pragma unroll
      for (int r = 0; r < 4; ++r)
        Osh[wave][quad * 4 + r][dnt * 16 + lrow] = oacc[mt][dnt][r];
    __syncthreads();   // Osh (and, first iter, psums) visible

    {
      const int q16 = tid >> 4;            // [0,16)
      const int d0  = (tid & 15) * 4;      // [0,64) step 4
      float4 a0 = *(const float4*)(&Osh[0][q16][d0]);
      float4 a1 = *(const float4*)(&Osh[1][q16][d0]);
      float4 a2 = *(const float4*)(&Osh[2][q16][d0]);
      float4 a3 = *(const float4*)(&Osh[3][q16][d0]);
      float4 res;
      res.x = (a0.x + a1.x) + (a2.x + a3.x);
      res.y = (a0.y + a1.y) + (a2.y + a3.y);
      res.z = (a0.z + a1.z) + (a2.z + a3.z);
      res.w = (a0.w + a1.w) + (a2.w + a3.w);
      *(float4*)(OPg + (opbase + mt * 16 + q16) * DH + d0) = res;
    }
    if (mt == 0 && tid < 64) {
      const float tot = (psums[0][tid] + psums[1][tid]) + (psums[2][tid] + psums[3][tid]);
      PSg[opbase + tid] = tot;
    }
    __syncthreads();   // reads done before next-mt overwrite
  }
}

// ---------------- kernel 3: out = merge(Opart)/denom @ wo + bo ----------------
// grid 1024: blk = b*256 + nb*2 + cs. Block = 8 rows x 128 out-cols.
__global__ __launch_bounds__(256, 4) void out_kernel(
    const float* __restrict__ OPg, const float* __restrict__ PSg,
    const float* __restrict__ wo, const float* __restrict__ bo,
    float* __restrict__ out)
{
  const int tid = threadIdx.x;
  const int cs  = blockIdx.x & 1;
  const int nb  = (blockIdx.x >> 1) & 127;
  const int b   = blockIdx.x >> 8;
  const int n0  = nb * 8;

  __shared__ __align__(16) float os[8][512];
  __shared__ float invs[8][8];     // [r][h]

  if (tid < 64) {
    const int r = tid >> 3, h = tid & 7;
    const size_t row = (size_t)b * SEQ + h * NSEQ + n0 + r;
    invs[r][h] = 1.0f / (PSg[row] + PSg[(size_t)B_ * SEQ + row]);
  }
  __syncthreads();

  for (int i = tid; i < 8 * 512; i += 256) {
    const int r = i >> 9, cc = i & 511;
    const size_t idx = ((size_t)b * SEQ + (cc >> 6) * NSEQ + n0 + r) * DH + (cc & 63);
    os[r][cc] = (OPg[idx] + OPg[(size_t)B_ * SEQ * DH + idx]) * invs[r][cc >> 6];
  }
  __syncthreads();

  const int rh = tid >> 5;                  // row [0,8)
  const int o  = cs * 128 + (tid & 31) * 4; // out col
  float a0 = 0.f, a1 = 0.f, a2 = 0.f, a3 = 0.f;

  for (int jb = 0; jb < 128; ++jb) {
    const float4 ov = *(const float4*)(&os[rh][jb * 4]);
    const float4 w0 = *(const float4*)(wo + (jb * 4 + 0) * QS + o);
    const float4 w1 = *(const float4*)(wo + (jb * 4 + 1) * QS + o);
    const float4 w2 = *(const float4*)(wo + (jb * 4 + 2) * QS + o);
    const float4 w3 = *(const float4*)(wo + (jb * 4 + 3) * QS + o);
    a0 += ov.x * w0.x + ov.y * w1.x + ov.z * w2.x + ov.w * w3.x;
    a1 += ov.x * w0.y + ov.y * w1.y + ov.z * w2.y + ov.w * w3.y;
    a2 += ov.x * w0.z + ov.y * w1.z + ov.z * w2.z + ov.w * w3.z;
    a3 += ov.x * w0.w + ov.y * w1.w + ov.z * w2.w + ov.w * w3.w;
  }

  const float4 bv = *(const float4*)(bo + o);
  float4 res;
  res.x = a0 + bv.x; res.y = a1 + bv.y; res.z = a2 + bv.z; res.w = a3 + bv.w;
  *(float4*)(out + ((size_t)b * NSEQ + n0 + rh) * QS + o) = res;
}

extern "C" void kernel_launch(void* const* d_in, const int* in_sizes, int n_in,
                              void* d_out, int out_size, void* d_ws, size_t ws_size,
                              hipStream_t stream) {
  const float* x   = (const float*)d_in[0];
  const float* wq1 = (const float*)d_in[1];
  const float* wq2 = (const float*)d_in[2];
  const float* wk1 = (const float*)d_in[3];
  const float* wk2 = (const float*)d_in[4];
  const float* wv1 = (const float*)d_in[5];
  const float* wv2 = (const float*)d_in[6];
  const float* wo  = (const float*)d_in[7];
  const float* bo  = (const float*)d_in[8];
  float* out = (float*)d_out;

  __hip_bfloat16* Qg  = (__hip_bfloat16*)d_ws;
  __hip_bfloat16* KSg = Qg + (size_t)B_ * SEQ * DH;
  __hip_bfloat16* VSg = KSg + (size_t)B_ * KVSW_BATCH;
  float*          OPg = (float*)(VSg + (size_t)B_ * KVSW_BATCH);   // [2][B_][SEQ][DH]
  float*          PSg = OPg + 2 * (size_t)B_ * SEQ * DH;           // [2][B_][SEQ]

  qkv_kernel<<<768, 256, 0, stream>>>(x, wq1, wq2, wk1, wk2, wv1, wv2, Qg, KSg, VSg);
  attn_kernel<<<1024, 256, 0, stream>>>(Qg, KSg, VSg, OPg, PSg);
  out_kernel<<<1024, 256, 0, stream>>>(OPg, PSg, wo, bo, out);
}

// Round 8
// 568.272 us; speedup vs baseline: 1.8229x; 1.7419x over previous
//
#include <hip/hip_runtime.h>
#include <hip/hip_bf16.h>

// CrossAttention: b=4, n=1024, qs=256, heads=8, dim_head=64, bottleneck=40.
// Attention = full 8192x8192 softmax-attention per batch over D=64.
//
// R8: register-budget round. gfx950 unifies VGPR+AGPR: oacc's 64 fp32
// accumulators count against the same per-wave budget, so R6/R7's
// launch_bounds demanded caps (128/170) the ~184-reg working set couldn't
// meet -> scratch spill (2.3GB HBM traffic). Fix: single PairBuf (-32 regs,
// compiler re-pipelines under unroll 2) + launch_bounds(256,3) -> ~155-169
// total <= 170 cap, 3 blocks/CU, no spill.
//
// Workspace: Q 4MB | K_sw 4MB | V_sw 4MB | Opart 2x8MB | psum 2x128KB ~ 28.3MB.

#define B_    4
#define H_    8
#define NSEQ  1024
#define SEQ   8192        // H_*NSEQ
#define DH    64
#define QS    256
#define INNER 512
#define QSCALE 0.18033688011112042f   // (1/sqrt(64)) * log2(e)

#define KVSW_BATCH 524288             // elems per batch in K_sw / V_sw

typedef __bf16 bf16x8 __attribute__((ext_vector_type(8)));
typedef float floatx4 __attribute__((ext_vector_type(4)));

// ---------------- kernel 1: QKV projections + fragment-order swizzle ----------------
// grid 768: blk = p*256 + b*64 + nblk. One projection per block, 16 x-rows.
__global__ __launch_bounds__(256, 3) void qkv_kernel(
    const float* __restrict__ x,
    const float* __restrict__ wq1, const float* __restrict__ wq2,
    const float* __restrict__ wk1, const float* __restrict__ wk2,
    const float* __restrict__ wv1, const float* __restrict__ wv2,
    __hip_bfloat16* __restrict__ Qg, __hip_bfloat16* __restrict__ KSg,
    __hip_bfloat16* __restrict__ VSg)
{
  const int tid  = threadIdx.x;
  const int p    = blockIdx.x >> 8;          // 0=Q 1=K 2=V
  const int rem  = blockIdx.x & 255;
  const int b    = rem >> 6;
  const int nblk = rem & 63;
  const int n0   = nblk << 4;

  __shared__ __align__(16) float xs[16][260];
  __shared__ __align__(16) float tb[16][40];
  __shared__ __align__(16) __hip_bfloat16 ob[10240];     // p<2: [16][520]; p==2: [512][20]

  const float* w1 = (p == 0) ? wq1 : (p == 1) ? wk1 : wv1;
  const float* w2 = (p == 0) ? wq2 : (p == 1) ? wk2 : wv2;

  for (int i = tid; i < 16 * 256; i += 256) {
    const int r = i >> 8, c = i & 255;
    xs[r][c] = x[((size_t)b * NSEQ + n0 + r) * QS + c];
  }
  __syncthreads();

  if (tid < 160) {
    const int r  = tid / 10;
    const int bn = (tid - r * 10) * 4;
    float a0 = 0.f, a1 = 0.f, a2 = 0.f, a3 = 0.f;
    for (int c4 = 0; c4 < 64; ++c4) {
      const float4 xv = *(const float4*)(&xs[r][c4 * 4]);
      const float4 wa = *(const float4*)(w1 + (c4 * 4 + 0) * 40 + bn);
      const float4 wb = *(const float4*)(w1 + (c4 * 4 + 1) * 40 + bn);
      const float4 wc = *(const float4*)(w1 + (c4 * 4 + 2) * 40 + bn);
      const float4 wd = *(const float4*)(w1 + (c4 * 4 + 3) * 40 + bn);
      a0 += xv.x * wa.x + xv.y * wb.x + xv.z * wc.x + xv.w * wd.x;
      a1 += xv.x * wa.y + xv.y * wb.y + xv.z * wc.y + xv.w * wd.y;
      a2 += xv.x * wa.z + xv.y * wb.z + xv.z * wc.z + xv.w * wd.z;
      a3 += xv.x * wa.w + xv.y * wb.w + xv.z * wc.w + xv.w * wd.w;
    }
    if (p == 1) {   // SiLU on K bottleneck
      a0 = a0 / (1.f + __expf(-a0));
      a1 = a1 / (1.f + __expf(-a1));
      a2 = a2 / (1.f + __expf(-a2));
      a3 = a3 / (1.f + __expf(-a3));
    }
    tb[r][bn + 0] = a0; tb[r][bn + 1] = a1;
    tb[r][bn + 2] = a2; tb[r][bn + 3] = a3;
  }
  __syncthreads();

  const float scale = (p == 0) ? QSCALE : 1.0f;
  #pragma unroll
  for (int pass = 0; pass < 2; ++pass) {
    const int task = tid + pass * 256;
    const int cq = task & 127;
    const int rq = (task >> 7) & 3;
    const int c  = cq * 4, r0 = rq * 4;
    float acc[4][4];
    #pragma unroll
    for (int i = 0; i < 4; ++i)
      #pragma unroll
      for (int j = 0; j < 4; ++j) acc[i][j] = 0.f;

    for (int jb = 0; jb < 10; ++jb) {
      const float4 w0 = *(const float4*)(w2 + (jb * 4 + 0) * INNER + c);
      const float4 w1r = *(const float4*)(w2 + (jb * 4 + 1) * INNER + c);
      const float4 w2r = *(const float4*)(w2 + (jb * 4 + 2) * INNER + c);
      const float4 w3 = *(const float4*)(w2 + (jb * 4 + 3) * INNER + c);
      #pragma unroll
      for (int ri = 0; ri < 4; ++ri) {
        const float4 tv = *(const float4*)(&tb[r0 + ri][jb * 4]);
        acc[ri][0] += tv.x * w0.x + tv.y * w1r.x + tv.z * w2r.x + tv.w * w3.x;
        acc[ri][1] += tv.x * w0.y + tv.y * w1r.y + tv.z * w2r.y + tv.w * w3.y;
        acc[ri][2] += tv.x * w0.z + tv.y * w1r.z + tv.z * w2r.z + tv.w * w3.z;
        acc[ri][3] += tv.x * w0.w + tv.y * w1r.w + tv.z * w2r.w + tv.w * w3.w;
      }
    }
    #pragma unroll
    for (int ri = 0; ri < 4; ++ri)
      #pragma unroll
      for (int ci = 0; ci < 4; ++ci) {
        const int cc = c + ci;
        const float v = acc[ri][ci] * scale;
        if (p < 2) ob[(r0 + ri) * 520 + cc] = __float2bfloat16(v);
        else       ob[cc * 20 + (r0 + ri)]  = __float2bfloat16(v);
      }
  }
  __syncthreads();

  if (p == 0) {
    const int row = tid >> 4;
    const int col = (tid & 15) * 32;
    const int h = col >> 6, d0 = col & 63;
    __hip_bfloat16* dst = Qg + ((size_t)b * SEQ + h * NSEQ + n0 + row) * DH + d0;
    #pragma unroll
    for (int i = 0; i < 4; ++i)
      *(float4*)(dst + i * 8) = *(const float4*)(&ob[row * 520 + col + i * 8]);
  } else if (p == 1) {
    #pragma unroll
    for (int cc4 = 0; cc4 < 4; ++cc4) {
      const int c    = tid + cc4 * 256;
      const int h    = c >> 7;
      const int ks   = (c >> 6) & 1;
      const int lane = c & 63;
      const int lrow = lane & 15, quad = lane >> 4;
      const int t    = h * 64 + nblk;
      const size_t dst = (size_t)b * KVSW_BATCH + ((size_t)(t * 2 + ks) * 64 + lane) * 8;
      *(float4*)(KSg + dst) = *(const float4*)(&ob[lrow * 520 + h * 64 + ks * 32 + quad * 8]);
    }
  } else {
    const int st = nblk & 1;
    #pragma unroll
    for (int cc8 = 0; cc8 < 8; ++cc8) {
      const int c    = tid + cc8 * 256;
      const int h    = c >> 8;
      const int dnt  = (c >> 6) & 3;
      const int lane = c & 63;
      const int lrow = lane & 15, quad = lane >> 4;
      const int pp   = h * 32 + (nblk >> 1);
      const size_t dst = (size_t)b * KVSW_BATCH + ((size_t)(pp * 4 + dnt) * 64 + lane) * 8 + st * 4;
      *(uint2*)(VSg + dst) = *(const uint2*)(&ob[(h * 64 + dnt * 16 + lrow) * 20 + quad * 4]);
    }
  }
}

// ---------------- kernel 2: attention, kv-split partial blocks ----------------
// grid 1024: xcd=blk&7 (b=xcd>>1), idx=blk>>3: half=idx&1, qt=idx>>1.
// Block = 4 waves x 64 q-rows x 4096 kv (each wave a private 1024-kv range).
// Emits partial O (fp32) + partial softmax denominator; out_kernel merges.
struct PairBuf {
  bf16x8 k[2][2];   // [strip][k-span]
  bf16x8 v[4];      // [d-tile]
};

__global__ __launch_bounds__(256, 3) void attn_kernel(
    const __hip_bfloat16* __restrict__ Qg,
    const __hip_bfloat16* __restrict__ KSg,
    const __hip_bfloat16* __restrict__ VSg,
    float* __restrict__ OPg,       // [2][B_][SEQ][DH]
    float* __restrict__ PSg)       // [2][B_][SEQ]
{
  __shared__ float Osh[4][16][68];
  __shared__ float psums[4][64];

  const int tid  = threadIdx.x;
  const int wave = tid >> 6;
  const int lane = tid & 63;
  const int lrow = lane & 15;
  const int quad = lane >> 4;

  const int xcd   = blockIdx.x & 7;
  const int idx   = blockIdx.x >> 3;       // [0,128)
  const int b     = xcd >> 1;
  const int half  = idx & 1;
  const int qtile = (xcd & 1) * 64 + (idx >> 1);
  const int qbase = qtile * 64;

  const __hip_bfloat16* Qb  = Qg + ((size_t)b * SEQ + qbase) * DH;
  const __hip_bfloat16* kp0 = KSg + (size_t)b * KVSW_BATCH + half * 262144
                              + (size_t)wave * 65536 + lane * 8;
  const __hip_bfloat16* vp0 = VSg + (size_t)b * KVSW_BATCH + half * 262144
                              + (size_t)wave * 65536 + lane * 8;

  bf16x8 qf[4][2];
  #pragma unroll
  for (int mt = 0; mt < 4; ++mt)
    #pragma unroll
    for (int s = 0; s < 2; ++s)
      qf[mt][s] = *(const bf16x8*)(Qb + (mt * 16 + lrow) * DH + s * 32 + quad * 8);

  floatx4 oacc[4][4];   // [mt][dnt] — 64 acc regs (unified budget!)
  #pragma unroll
  for (int mt = 0; mt < 4; ++mt)
    #pragma unroll
    for (int dnt = 0; dnt < 4; ++dnt)
      oacc[mt][dnt] = (floatx4){0.f, 0.f, 0.f, 0.f};
  float psum[4] = {0.f, 0.f, 0.f, 0.f};

  // single-buffer loop: loads at top, fused per-mt QK->exp2->PV. unroll 2
  // lets the compiler overlap next-iter loads with current compute within
  // the (256,3) register cap — no explicit dbuf registers.
  #pragma unroll 2
  for (int pair = 0; pair < 32; ++pair) {
    PairBuf pb;
    const __hip_bfloat16* kp = kp0 + pair * 2048;
    pb.k[0][0] = *(const bf16x8*)(kp);
    pb.k[0][1] = *(const bf16x8*)(kp + 512);
    pb.k[1][0] = *(const bf16x8*)(kp + 1024);
    pb.k[1][1] = *(const bf16x8*)(kp + 1536);
    const __hip_bfloat16* vp = vp0 + pair * 2048;
    #pragma unroll
    for (int dnt = 0; dnt < 4; ++dnt)
      pb.v[dnt] = *(const bf16x8*)(vp + dnt * 512);

    #pragma unroll
    for (int mt = 0; mt < 4; ++mt) {
      floatx4 s0 = (floatx4){0.f, 0.f, 0.f, 0.f};
      floatx4 s1 = (floatx4){0.f, 0.f, 0.f, 0.f};
      s0 = __builtin_amdgcn_mfma_f32_16x16x32_bf16(pb.k[0][0], qf[mt][0], s0, 0, 0, 0);
      s0 = __builtin_amdgcn_mfma_f32_16x16x32_bf16(pb.k[0][1], qf[mt][1], s0, 0, 0, 0);
      s1 = __builtin_amdgcn_mfma_f32_16x16x32_bf16(pb.k[1][0], qf[mt][0], s1, 0, 0, 0);
      s1 = __builtin_amdgcn_mfma_f32_16x16x32_bf16(pb.k[1][1], qf[mt][1], s1, 0, 0, 0);
      float p[8];
      #pragma unroll
      for (int r = 0; r < 4; ++r) {
        p[r]     = __builtin_amdgcn_exp2f(s0[r]);
        p[4 + r] = __builtin_amdgcn_exp2f(s1[r]);
      }
      psum[mt] += ((p[0] + p[1]) + (p[2] + p[3])) + ((p[4] + p[5]) + (p[6] + p[7]));
      bf16x8 pa;
      #pragma unroll
      for (int j = 0; j < 8; ++j) pa[j] = (__bf16)p[j];
      #pragma unroll
      for (int dnt = 0; dnt < 4; ++dnt)
        oacc[mt][dnt] = __builtin_amdgcn_mfma_f32_16x16x32_bf16(pa, pb.v[dnt], oacc[mt][dnt], 0, 0, 0);
    }
  }

  // quad-reduce psum, publish per-wave partials
  #pragma unroll
  for (int mt = 0; mt < 4; ++mt) {
    float s = psum[mt];
    s += __shfl_xor(s, 16, 64);
    s += __shfl_xor(s, 32, 64);
    psum[mt] = s;
  }
  if (quad == 0) {
    #pragma unroll
    for (int mt = 0; mt < 4; ++mt)
      psums[wave][mt * 16 + lrow] = psum[mt];
  }

  const size_t opbase = ((size_t)half * B_ + b) * SEQ + qbase;

  // chunked cross-wave O reduction (per 16-q tile); partials, no normalize
  #pragma unroll
  for (int mt = 0; mt < 4; ++mt) {
    #pragma unroll
    for (int dnt = 0; dnt < 4; ++dnt)
      #pragma unroll
      for (int r = 0; r < 4; ++r)
        Osh[wave][quad * 4 + r][dnt * 16 + lrow] = oacc[mt][dnt][r];
    __syncthreads();   // Osh (and, first iter, psums) visible

    {
      const int q16 = tid >> 4;            // [0,16)
      const int d0  = (tid & 15) * 4;      // [0,64) step 4
      float4 a0 = *(const float4*)(&Osh[0][q16][d0]);
      float4 a1 = *(const float4*)(&Osh[1][q16][d0]);
      float4 a2 = *(const float4*)(&Osh[2][q16][d0]);
      float4 a3 = *(const float4*)(&Osh[3][q16][d0]);
      float4 res;
      res.x = (a0.x + a1.x) + (a2.x + a3.x);
      res.y = (a0.y + a1.y) + (a2.y + a3.y);
      res.z = (a0.z + a1.z) + (a2.z + a3.z);
      res.w = (a0.w + a1.w) + (a2.w + a3.w);
      *(float4*)(OPg + (opbase + mt * 16 + q16) * DH + d0) = res;
    }
    if (mt == 0 && tid < 64) {
      const float tot = (psums[0][tid] + psums[1][tid]) + (psums[2][tid] + psums[3][tid]);
      PSg[opbase + tid] = tot;
    }
    __syncthreads();   // reads done before next-mt overwrite
  }
}

// ---------------- kernel 3: out = merge(Opart)/denom @ wo + bo ----------------
// grid 1024: blk = b*256 + nb*2 + cs. Block = 8 rows x 128 out-cols.
__global__ __launch_bounds__(256, 4) void out_kernel(
    const float* __restrict__ OPg, const float* __restrict__ PSg,
    const float* __restrict__ wo, const float* __restrict__ bo,
    float* __restrict__ out)
{
  const int tid = threadIdx.x;
  const int cs  = blockIdx.x & 1;
  const int nb  = (blockIdx.x >> 1) & 127;
  const int b   = blockIdx.x >> 8;
  const int n0  = nb * 8;

  __shared__ __align__(16) float os[8][512];
  __shared__ float invs[8][8];     // [r][h]

  if (tid < 64) {
    const int r = tid >> 3, h = tid & 7;
    const size_t row = (size_t)b * SEQ + h * NSEQ + n0 + r;
    invs[r][h] = 1.0f / (PSg[row] + PSg[(size_t)B_ * SEQ + row]);
  }
  __syncthreads();

  for (int i = tid; i < 8 * 512; i += 256) {
    const int r = i >> 9, cc = i & 511;
    const size_t idx = ((size_t)b * SEQ + (cc >> 6) * NSEQ + n0 + r) * DH + (cc & 63);
    os[r][cc] = (OPg[idx] + OPg[(size_t)B_ * SEQ * DH + idx]) * invs[r][cc >> 6];
  }
  __syncthreads();

  const int rh = tid >> 5;                  // row [0,8)
  const int o  = cs * 128 + (tid & 31) * 4; // out col
  float a0 = 0.f, a1 = 0.f, a2 = 0.f, a3 = 0.f;

  for (int jb = 0; jb < 128; ++jb) {
    const float4 ov = *(const float4*)(&os[rh][jb * 4]);
    const float4 w0 = *(const float4*)(wo + (jb * 4 + 0) * QS + o);
    const float4 w1 = *(const float4*)(wo + (jb * 4 + 1) * QS + o);
    const float4 w2 = *(const float4*)(wo + (jb * 4 + 2) * QS + o);
    const float4 w3 = *(const float4*)(wo + (jb * 4 + 3) * QS + o);
    a0 += ov.x * w0.x + ov.y * w1.x + ov.z * w2.x + ov.w * w3.x;
    a1 += ov.x * w0.y + ov.y * w1.y + ov.z * w2.y + ov.w * w3.y;
    a2 += ov.x * w0.z + ov.y * w1.z + ov.z * w2.z + ov.w * w3.z;
    a3 += ov.x * w0.w + ov.y * w1.w + ov.z * w2.w + ov.w * w3.w;
  }

  const float4 bv = *(const float4*)(bo + o);
  float4 res;
  res.x = a0 + bv.x; res.y = a1 + bv.y; res.z = a2 + bv.z; res.w = a3 + bv.w;
  *(float4*)(out + ((size_t)b * NSEQ + n0 + rh) * QS + o) = res;
}

extern "C" void kernel_launch(void* const* d_in, const int* in_sizes, int n_in,
                              void* d_out, int out_size, void* d_ws, size_t ws_size,
                              hipStream_t stream) {
  const float* x   = (const float*)d_in[0];
  const float* wq1 = (const float*)d_in[1];
  const float* wq2 = (const float*)d_in[2];
  const float* wk1 = (const float*)d_in[3];
  const float* wk2 = (const float*)d_in[4];
  const float* wv1 = (const float*)d_in[5];
  const float* wv2 = (const float*)d_in[6];
  const float* wo  = (const float*)d_in[7];
  const float* bo  = (const float*)d_in[8];
  float* out = (float*)d_out;

  __hip_bfloat16* Qg  = (__hip_bfloat16*)d_ws;
  __hip_bfloat16* KSg = Qg + (size_t)B_ * SEQ * DH;
  __hip_bfloat16* VSg = KSg + (size_t)B_ * KVSW_BATCH;
  float*          OPg = (float*)(VSg + (size_t)B_ * KVSW_BATCH);   // [2][B_][SEQ][DH]
  float*          PSg = OPg + 2 * (size_t)B_ * SEQ * DH;           // [2][B_][SEQ]

  qkv_kernel<<<768, 256, 0, stream>>>(x, wq1, wq2, wk1, wk2, wv1, wv2, Qg, KSg, VSg);
  attn_kernel<<<1024, 256, 0, stream>>>(Qg, KSg, VSg, OPg, PSg);
  out_kernel<<<1024, 256, 0, stream>>>(OPg, PSg, wo, bo, out);
}

// Round 9
// 233.832 us; speedup vs baseline: 4.4301x; 2.4303x over previous
//
#include <hip/hip_runtime.h>
#include <hip/hip_bf16.h>

// CrossAttention: b=4, n=1024, qs=256, heads=8, dim_head=64, bottleneck=40.
// Attention = full 8192x8192 softmax-attention per batch over D=64.
//
// R9: qkv reverted to the R5-proven MONOLITHIC shape (all 3 projections per
// block — measured 3.6MB fetch vs the R6 per-projection split's 1.04GB
// L2-thrash), now at 8 rows/block (grid 512, 2 blocks/CU) to fix R5's
// 1-block/CU latency ceiling. attn (R8, spill-free) and out kept verbatim.
//
// Workspace: Q 4MB | K_sw 4MB | V_sw 4MB | Opart 2x8MB | psum 2x128KB ~ 28.3MB.

#define B_    4
#define H_    8
#define NSEQ  1024
#define SEQ   8192        // H_*NSEQ
#define DH    64
#define QS    256
#define INNER 512
#define QSCALE 0.18033688011112042f   // (1/sqrt(64)) * log2(e)

#define KVSW_BATCH 524288             // elems per batch in K_sw / V_sw

typedef __bf16 bf16x8 __attribute__((ext_vector_type(8)));
typedef float floatx4 __attribute__((ext_vector_type(4)));

// ---------------- kernel 1: QKV projections + fragment-order swizzle ----------------
// grid 512: b = blk>>7, nb8 = blk&127 -> 8 x-rows. All 3 projections per block.
//   Qg  [b][h*1024+n][64]                      (row-major)
//   KSg flat: b*KVSW + t16*1024 + ks*512 + lane*8 + j
//       t16=kv>>4, ks=dl>>5, lane=((dl>>3)&3)*16 + (kv&15), j=dl&7   (dl=d&63)
//   VSg flat: b*KVSW + p32*2048 + dnt*512 + lane*8 + j
//       p32=kv>>5(+h*32), dnt=(d&63)>>4, lane=((kv>>2)&3)*16+(d&15),
//       j=((kv>>4)&1)*4+(kv&3)
__global__ __launch_bounds__(256) void qkv_kernel(
    const float* __restrict__ x,
    const float* __restrict__ wq1, const float* __restrict__ wq2,
    const float* __restrict__ wk1, const float* __restrict__ wk2,
    const float* __restrict__ wv1, const float* __restrict__ wv2,
    __hip_bfloat16* __restrict__ Qg, __hip_bfloat16* __restrict__ KSg,
    __hip_bfloat16* __restrict__ VSg)
{
  const int tid = threadIdx.x;
  const int b   = blockIdx.x >> 7;
  const int nb8 = blockIdx.x & 127;
  const int n0  = nb8 << 3;

  __shared__ __align__(16) float xs[8][260];
  __shared__ __align__(16) float tb[3][8][40];
  __shared__ __align__(16) __hip_bfloat16 qb[8][520];
  __shared__ __align__(16) __hip_bfloat16 kb[8][520];
  __shared__ __align__(16) __hip_bfloat16 vb[512][12];   // [h*64+d][n_local]

  for (int i = tid; i < 8 * 256; i += 256) {
    const int r = i >> 8, c = i & 255;
    xs[r][c] = x[((size_t)b * NSEQ + n0 + r) * QS + c];
  }
  __syncthreads();

  // stage 1: bottleneck. 240 tasks = 3 proj x 8 rows x 10 col-quads.
  if (tid < 240) {
    const int p   = tid / 80;
    const int rem = tid - p * 80;
    const int r   = rem / 10;
    const int bn  = (rem - r * 10) * 4;
    const float* w1 = (p == 0) ? wq1 : (p == 1) ? wk1 : wv1;
    float a0 = 0.f, a1 = 0.f, a2 = 0.f, a3 = 0.f;
    for (int c4 = 0; c4 < 64; ++c4) {
      const float4 xv = *(const float4*)(&xs[r][c4 * 4]);
      const float4 wa = *(const float4*)(w1 + (c4 * 4 + 0) * 40 + bn);
      const float4 wb = *(const float4*)(w1 + (c4 * 4 + 1) * 40 + bn);
      const float4 wc = *(const float4*)(w1 + (c4 * 4 + 2) * 40 + bn);
      const float4 wd = *(const float4*)(w1 + (c4 * 4 + 3) * 40 + bn);
      a0 += xv.x * wa.x + xv.y * wb.x + xv.z * wc.x + xv.w * wd.x;
      a1 += xv.x * wa.y + xv.y * wb.y + xv.z * wc.y + xv.w * wd.y;
      a2 += xv.x * wa.z + xv.y * wb.z + xv.z * wc.z + xv.w * wd.z;
      a3 += xv.x * wa.w + xv.y * wb.w + xv.z * wc.w + xv.w * wd.w;
    }
    if (p == 1) {   // SiLU on K bottleneck
      a0 = a0 / (1.f + __expf(-a0));
      a1 = a1 / (1.f + __expf(-a1));
      a2 = a2 / (1.f + __expf(-a2));
      a3 = a3 / (1.f + __expf(-a3));
    }
    tb[p][r][bn + 0] = a0; tb[p][r][bn + 1] = a1;
    tb[p][r][bn + 2] = a2; tb[p][r][bn + 3] = a3;
  }
  __syncthreads();

  // stage 2: 40 -> 512. 768 tasks in 3 passes; pass == projection (uniform).
  #pragma unroll
  for (int pass = 0; pass < 3; ++pass) {
    const int p  = pass;
    const int cq = tid & 127;
    const int rq = (tid >> 7) & 1;
    const int c  = cq * 4, r0 = rq * 4;
    const float* w2 = (p == 0) ? wq2 : (p == 1) ? wk2 : wv2;
    const float scale = (p == 0) ? QSCALE : 1.0f;
    float acc[4][4];
    #pragma unroll
    for (int i = 0; i < 4; ++i)
      #pragma unroll
      for (int j = 0; j < 4; ++j) acc[i][j] = 0.f;

    for (int jb = 0; jb < 10; ++jb) {
      const float4 w0 = *(const float4*)(w2 + (jb * 4 + 0) * INNER + c);
      const float4 w1r = *(const float4*)(w2 + (jb * 4 + 1) * INNER + c);
      const float4 w2r = *(const float4*)(w2 + (jb * 4 + 2) * INNER + c);
      const float4 w3 = *(const float4*)(w2 + (jb * 4 + 3) * INNER + c);
      #pragma unroll
      for (int ri = 0; ri < 4; ++ri) {
        const float4 tv = *(const float4*)(&tb[p][r0 + ri][jb * 4]);
        acc[ri][0] += tv.x * w0.x + tv.y * w1r.x + tv.z * w2r.x + tv.w * w3.x;
        acc[ri][1] += tv.x * w0.y + tv.y * w1r.y + tv.z * w2r.y + tv.w * w3.y;
        acc[ri][2] += tv.x * w0.z + tv.y * w1r.z + tv.z * w2r.z + tv.w * w3.z;
        acc[ri][3] += tv.x * w0.w + tv.y * w1r.w + tv.z * w2r.w + tv.w * w3.w;
      }
    }
    #pragma unroll
    for (int ri = 0; ri < 4; ++ri)
      #pragma unroll
      for (int ci = 0; ci < 4; ++ci) {
        const int cc = c + ci;
        const float v = acc[ri][ci] * scale;
        if (p == 0)      qb[r0 + ri][cc] = __float2bfloat16(v);
        else if (p == 1) kb[r0 + ri][cc] = __float2bfloat16(v);
        else             vb[cc][r0 + ri] = __float2bfloat16(v);
      }
  }
  __syncthreads();

  // ---- Q write: 512 float4 tasks (h, r, d8); 1KB contiguous per wave ----
  for (int i = tid; i < 512; i += 256) {
    const int h  = i >> 6;
    const int r  = (i >> 3) & 7;
    const int d8 = i & 7;
    *(float4*)(Qg + ((size_t)b * SEQ + h * NSEQ + n0 + r) * DH + d8 * 8) =
        *(const float4*)(&qb[r][h * 64 + d8 * 8]);
  }

  // ---- K_sw write: 512 float4 tasks (h, ks, quad, r) ----
  for (int i = tid; i < 512; i += 256) {
    const int h    = i >> 6;
    const int ks   = (i >> 5) & 1;
    const int quad = (i >> 3) & 3;
    const int r    = i & 7;
    const int lane = quad * 16 + (nb8 & 1) * 8 + r;
    const size_t dst = (size_t)b * KVSW_BATCH
        + ((size_t)((h * 64 + (nb8 >> 1)) * 2 + ks) * 64 + lane) * 8;
    *(float4*)(KSg + dst) = *(const float4*)(&kb[r][h * 64 + ks * 32 + quad * 8]);
  }

  // ---- V_sw write: 1024 uint2 tasks (g, d) ----
  for (int i = tid; i < 1024; i += 256) {
    const int g   = i >> 9;          // which 4-row group of this block's 8 rows
    const int d   = i & 511;         // h*64 + dnt*16 + dm
    const int h   = d >> 6;
    const int dnt = (d >> 4) & 3;
    const int dm  = d & 15;
    const int lane = ((nb8 * 2 + g) & 3) * 16 + dm;
    const size_t dst = (size_t)b * KVSW_BATCH
        + ((size_t)((h * 32 + (nb8 >> 2)) * 4 + dnt) * 64 + lane) * 8
        + ((nb8 >> 1) & 1) * 4;
    *(uint2*)(VSg + dst) = *(const uint2*)(&vb[d][g * 4]);
  }
}

// ---------------- kernel 2: attention, kv-split partial blocks (R8, unchanged) ----------------
struct PairBuf {
  bf16x8 k[2][2];   // [strip][k-span]
  bf16x8 v[4];      // [d-tile]
};

__global__ __launch_bounds__(256, 3) void attn_kernel(
    const __hip_bfloat16* __restrict__ Qg,
    const __hip_bfloat16* __restrict__ KSg,
    const __hip_bfloat16* __restrict__ VSg,
    float* __restrict__ OPg,       // [2][B_][SEQ][DH]
    float* __restrict__ PSg)       // [2][B_][SEQ]
{
  __shared__ float Osh[4][16][68];
  __shared__ float psums[4][64];

  const int tid  = threadIdx.x;
  const int wave = tid >> 6;
  const int lane = tid & 63;
  const int lrow = lane & 15;
  const int quad = lane >> 4;

  const int xcd   = blockIdx.x & 7;
  const int idx   = blockIdx.x >> 3;       // [0,128)
  const int b     = xcd >> 1;
  const int half  = idx & 1;
  const int qtile = (xcd & 1) * 64 + (idx >> 1);
  const int qbase = qtile * 64;

  const __hip_bfloat16* Qb  = Qg + ((size_t)b * SEQ + qbase) * DH;
  const __hip_bfloat16* kp0 = KSg + (size_t)b * KVSW_BATCH + half * 262144
                              + (size_t)wave * 65536 + lane * 8;
  const __hip_bfloat16* vp0 = VSg + (size_t)b * KVSW_BATCH + half * 262144
                              + (size_t)wave * 65536 + lane * 8;

  bf16x8 qf[4][2];
  #pragma unroll
  for (int mt = 0; mt < 4; ++mt)
    #pragma unroll
    for (int s = 0; s < 2; ++s)
      qf[mt][s] = *(const bf16x8*)(Qb + (mt * 16 + lrow) * DH + s * 32 + quad * 8);

  floatx4 oacc[4][4];   // [mt][dnt] — 64 acc regs (unified budget)
  #pragma unroll
  for (int mt = 0; mt < 4; ++mt)
    #pragma unroll
    for (int dnt = 0; dnt < 4; ++dnt)
      oacc[mt][dnt] = (floatx4){0.f, 0.f, 0.f, 0.f};
  float psum[4] = {0.f, 0.f, 0.f, 0.f};

  #pragma unroll 2
  for (int pair = 0; pair < 32; ++pair) {
    PairBuf pb;
    const __hip_bfloat16* kp = kp0 + pair * 2048;
    pb.k[0][0] = *(const bf16x8*)(kp);
    pb.k[0][1] = *(const bf16x8*)(kp + 512);
    pb.k[1][0] = *(const bf16x8*)(kp + 1024);
    pb.k[1][1] = *(const bf16x8*)(kp + 1536);
    const __hip_bfloat16* vp = vp0 + pair * 2048;
    #pragma unroll
    for (int dnt = 0; dnt < 4; ++dnt)
      pb.v[dnt] = *(const bf16x8*)(vp + dnt * 512);

    #pragma unroll
    for (int mt = 0; mt < 4; ++mt) {
      floatx4 s0 = (floatx4){0.f, 0.f, 0.f, 0.f};
      floatx4 s1 = (floatx4){0.f, 0.f, 0.f, 0.f};
      s0 = __builtin_amdgcn_mfma_f32_16x16x32_bf16(pb.k[0][0], qf[mt][0], s0, 0, 0, 0);
      s0 = __builtin_amdgcn_mfma_f32_16x16x32_bf16(pb.k[0][1], qf[mt][1], s0, 0, 0, 0);
      s1 = __builtin_amdgcn_mfma_f32_16x16x32_bf16(pb.k[1][0], qf[mt][0], s1, 0, 0, 0);
      s1 = __builtin_amdgcn_mfma_f32_16x16x32_bf16(pb.k[1][1], qf[mt][1], s1, 0, 0, 0);
      float p[8];
      #pragma unroll
      for (int r = 0; r < 4; ++r) {
        p[r]     = __builtin_amdgcn_exp2f(s0[r]);
        p[4 + r] = __builtin_amdgcn_exp2f(s1[r]);
      }
      psum[mt] += ((p[0] + p[1]) + (p[2] + p[3])) + ((p[4] + p[5]) + (p[6] + p[7]));
      bf16x8 pa;
      #pragma unroll
      for (int j = 0; j < 8; ++j) pa[j] = (__bf16)p[j];
      #pragma unroll
      for (int dnt = 0; dnt < 4; ++dnt)
        oacc[mt][dnt] = __builtin_amdgcn_mfma_f32_16x16x32_bf16(pa, pb.v[dnt], oacc[mt][dnt], 0, 0, 0);
    }
  }

  #pragma unroll
  for (int mt = 0; mt < 4; ++mt) {
    float s = psum[mt];
    s += __shfl_xor(s, 16, 64);
    s += __shfl_xor(s, 32, 64);
    psum[mt] = s;
  }
  if (quad == 0) {
    #pragma unroll
    for (int mt = 0; mt < 4; ++mt)
      psums[wave][mt * 16 + lrow] = psum[mt];
  }

  const size_t opbase = ((size_t)half * B_ + b) * SEQ + qbase;

  #pragma unroll
  for (int mt = 0; mt < 4; ++mt) {
    #pragma unroll
    for (int dnt = 0; dnt < 4; ++dnt)
      #pragma unroll
      for (int r = 0; r < 4; ++r)
        Osh[wave][quad * 4 + r][dnt * 16 + lrow] = oacc[mt][dnt][r];
    __syncthreads();

    {
      const int q16 = tid >> 4;
      const int d0  = (tid & 15) * 4;
      float4 a0 = *(const float4*)(&Osh[0][q16][d0]);
      float4 a1 = *(const float4*)(&Osh[1][q16][d0]);
      float4 a2 = *(const float4*)(&Osh[2][q16][d0]);
      float4 a3 = *(const float4*)(&Osh[3][q16][d0]);
      float4 res;
      res.x = (a0.x + a1.x) + (a2.x + a3.x);
      res.y = (a0.y + a1.y) + (a2.y + a3.y);
      res.z = (a0.z + a1.z) + (a2.z + a3.z);
      res.w = (a0.w + a1.w) + (a2.w + a3.w);
      *(float4*)(OPg + (opbase + mt * 16 + q16) * DH + d0) = res;
    }
    if (mt == 0 && tid < 64) {
      const float tot = (psums[0][tid] + psums[1][tid]) + (psums[2][tid] + psums[3][tid]);
      PSg[opbase + tid] = tot;
    }
    __syncthreads();
  }
}

// ---------------- kernel 3: out = merge(Opart)/denom @ wo + bo (R8, unchanged) ----------------
__global__ __launch_bounds__(256, 4) void out_kernel(
    const float* __restrict__ OPg, const float* __restrict__ PSg,
    const float* __restrict__ wo, const float* __restrict__ bo,
    float* __restrict__ out)
{
  const int tid = threadIdx.x;
  const int cs  = blockIdx.x & 1;
  const int nb  = (blockIdx.x >> 1) & 127;
  const int b   = blockIdx.x >> 8;
  const int n0  = nb * 8;

  __shared__ __align__(16) float os[8][512];
  __shared__ float invs[8][8];     // [r][h]

  if (tid < 64) {
    const int r = tid >> 3, h = tid & 7;
    const size_t row = (size_t)b * SEQ + h * NSEQ + n0 + r;
    invs[r][h] = 1.0f / (PSg[row] + PSg[(size_t)B_ * SEQ + row]);
  }
  __syncthreads();

  for (int i = tid; i < 8 * 512; i += 256) {
    const int r = i >> 9, cc = i & 511;
    const size_t idx = ((size_t)b * SEQ + (cc >> 6) * NSEQ + n0 + r) * DH + (cc & 63);
    os[r][cc] = (OPg[idx] + OPg[(size_t)B_ * SEQ * DH + idx]) * invs[r][cc >> 6];
  }
  __syncthreads();

  const int rh = tid >> 5;
  const int o  = cs * 128 + (tid & 31) * 4;
  float a0 = 0.f, a1 = 0.f, a2 = 0.f, a3 = 0.f;

  for (int jb = 0; jb < 128; ++jb) {
    const float4 ov = *(const float4*)(&os[rh][jb * 4]);
    const float4 w0 = *(const float4*)(wo + (jb * 4 + 0) * QS + o);
    const float4 w1 = *(const float4*)(wo + (jb * 4 + 1) * QS + o);
    const float4 w2 = *(const float4*)(wo + (jb * 4 + 2) * QS + o);
    const float4 w3 = *(const float4*)(wo + (jb * 4 + 3) * QS + o);
    a0 += ov.x * w0.x + ov.y * w1.x + ov.z * w2.x + ov.w * w3.x;
    a1 += ov.x * w0.y + ov.y * w1.y + ov.z * w2.y + ov.w * w3.y;
    a2 += ov.x * w0.z + ov.y * w1.z + ov.z * w2.z + ov.w * w3.z;
    a3 += ov.x * w0.w + ov.y * w1.w + ov.z * w2.w + ov.w * w3.w;
  }

  const float4 bv = *(const float4*)(bo + o);
  float4 res;
  res.x = a0 + bv.x; res.y = a1 + bv.y; res.z = a2 + bv.z; res.w = a3 + bv.w;
  *(float4*)(out + ((size_t)b * NSEQ + n0 + rh) * QS + o) = res;
}

extern "C" void kernel_launch(void* const* d_in, const int* in_sizes, int n_in,
                              void* d_out, int out_size, void* d_ws, size_t ws_size,
                              hipStream_t stream) {
  const float* x   = (const float*)d_in[0];
  const float* wq1 = (const float*)d_in[1];
  const float* wq2 = (const float*)d_in[2];
  const float* wk1 = (const float*)d_in[3];
  const float* wk2 = (const float*)d_in[4];
  const float* wv1 = (const float*)d_in[5];
  const float* wv2 = (const float*)d_in[6];
  const float* wo  = (const float*)d_in[7];
  const float* bo  = (const float*)d_in[8];
  float* out = (float*)d_out;

  __hip_bfloat16* Qg  = (__hip_bfloat16*)d_ws;
  __hip_bfloat16* KSg = Qg + (size_t)B_ * SEQ * DH;
  __hip_bfloat16* VSg = KSg + (size_t)B_ * KVSW_BATCH;
  float*          OPg = (float*)(VSg + (size_t)B_ * KVSW_BATCH);   // [2][B_][SEQ][DH]
  float*          PSg = OPg + 2 * (size_t)B_ * SEQ * DH;           // [2][B_][SEQ]

  qkv_kernel<<<512, 256, 0, stream>>>(x, wq1, wq2, wk1, wk2, wv1, wv2, Qg, KSg, VSg);
  attn_kernel<<<1024, 256, 0, stream>>>(Qg, KSg, VSg, OPg, PSg);
  out_kernel<<<1024, 256, 0, stream>>>(OPg, PSg, wo, bo, out);
}

// Round 10
// 203.699 us; speedup vs baseline: 5.0855x; 1.1479x over previous
//
#include <hip/hip_runtime.h>
#include <hip/hip_bf16.h>

// CrossAttention: b=4, n=1024, qs=256, heads=8, dim_head=64, bottleneck=40.
// Attention = full 8192x8192 softmax-attention per batch over D=64.
//
// R10: out_kernel rewrite (was 73us at 16.6% VALUBusy — per-wave wo
// streaming through L1 with no pipelining, VGPR=36). Now: grid 256
// (1 block/CU -> wo's 512KB crosses L2->L1 ~once per CU), thread = 4x4
// outputs, explicit ping-pong register prefetch of wo rows, os reads are
// wave-broadcast. qkv + attn unchanged from R9 for clean attribution.
//
// Workspace: Q 4MB | K_sw 4MB | V_sw 4MB | Opart 2x8MB | psum 2x128KB ~ 28.3MB.

#define B_    4
#define H_    8
#define NSEQ  1024
#define SEQ   8192        // H_*NSEQ
#define DH    64
#define QS    256
#define INNER 512
#define QSCALE 0.18033688011112042f   // (1/sqrt(64)) * log2(e)

#define KVSW_BATCH 524288             // elems per batch in K_sw / V_sw

typedef __bf16 bf16x8 __attribute__((ext_vector_type(8)));
typedef float floatx4 __attribute__((ext_vector_type(4)));

// ---------------- kernel 1: QKV projections + fragment-order swizzle (R9) ----------------
__global__ __launch_bounds__(256) void qkv_kernel(
    const float* __restrict__ x,
    const float* __restrict__ wq1, const float* __restrict__ wq2,
    const float* __restrict__ wk1, const float* __restrict__ wk2,
    const float* __restrict__ wv1, const float* __restrict__ wv2,
    __hip_bfloat16* __restrict__ Qg, __hip_bfloat16* __restrict__ KSg,
    __hip_bfloat16* __restrict__ VSg)
{
  const int tid = threadIdx.x;
  const int b   = blockIdx.x >> 7;
  const int nb8 = blockIdx.x & 127;
  const int n0  = nb8 << 3;

  __shared__ __align__(16) float xs[8][260];
  __shared__ __align__(16) float tb[3][8][40];
  __shared__ __align__(16) __hip_bfloat16 qb[8][520];
  __shared__ __align__(16) __hip_bfloat16 kb[8][520];
  __shared__ __align__(16) __hip_bfloat16 vb[512][12];   // [h*64+d][n_local]

  for (int i = tid; i < 8 * 256; i += 256) {
    const int r = i >> 8, c = i & 255;
    xs[r][c] = x[((size_t)b * NSEQ + n0 + r) * QS + c];
  }
  __syncthreads();

  // stage 1: bottleneck. 240 tasks = 3 proj x 8 rows x 10 col-quads.
  if (tid < 240) {
    const int p   = tid / 80;
    const int rem = tid - p * 80;
    const int r   = rem / 10;
    const int bn  = (rem - r * 10) * 4;
    const float* w1 = (p == 0) ? wq1 : (p == 1) ? wk1 : wv1;
    float a0 = 0.f, a1 = 0.f, a2 = 0.f, a3 = 0.f;
    for (int c4 = 0; c4 < 64; ++c4) {
      const float4 xv = *(const float4*)(&xs[r][c4 * 4]);
      const float4 wa = *(const float4*)(w1 + (c4 * 4 + 0) * 40 + bn);
      const float4 wb = *(const float4*)(w1 + (c4 * 4 + 1) * 40 + bn);
      const float4 wc = *(const float4*)(w1 + (c4 * 4 + 2) * 40 + bn);
      const float4 wd = *(const float4*)(w1 + (c4 * 4 + 3) * 40 + bn);
      a0 += xv.x * wa.x + xv.y * wb.x + xv.z * wc.x + xv.w * wd.x;
      a1 += xv.x * wa.y + xv.y * wb.y + xv.z * wc.y + xv.w * wd.y;
      a2 += xv.x * wa.z + xv.y * wb.z + xv.z * wc.z + xv.w * wd.z;
      a3 += xv.x * wa.w + xv.y * wb.w + xv.z * wc.w + xv.w * wd.w;
    }
    if (p == 1) {   // SiLU on K bottleneck
      a0 = a0 / (1.f + __expf(-a0));
      a1 = a1 / (1.f + __expf(-a1));
      a2 = a2 / (1.f + __expf(-a2));
      a3 = a3 / (1.f + __expf(-a3));
    }
    tb[p][r][bn + 0] = a0; tb[p][r][bn + 1] = a1;
    tb[p][r][bn + 2] = a2; tb[p][r][bn + 3] = a3;
  }
  __syncthreads();

  // stage 2: 40 -> 512. 3 passes; pass == projection (uniform).
  #pragma unroll
  for (int pass = 0; pass < 3; ++pass) {
    const int p  = pass;
    const int cq = tid & 127;
    const int rq = (tid >> 7) & 1;
    const int c  = cq * 4, r0 = rq * 4;
    const float* w2 = (p == 0) ? wq2 : (p == 1) ? wk2 : wv2;
    const float scale = (p == 0) ? QSCALE : 1.0f;
    float acc[4][4];
    #pragma unroll
    for (int i = 0; i < 4; ++i)
      #pragma unroll
      for (int j = 0; j < 4; ++j) acc[i][j] = 0.f;

    for (int jb = 0; jb < 10; ++jb) {
      const float4 w0 = *(const float4*)(w2 + (jb * 4 + 0) * INNER + c);
      const float4 w1r = *(const float4*)(w2 + (jb * 4 + 1) * INNER + c);
      const float4 w2r = *(const float4*)(w2 + (jb * 4 + 2) * INNER + c);
      const float4 w3 = *(const float4*)(w2 + (jb * 4 + 3) * INNER + c);
      #pragma unroll
      for (int ri = 0; ri < 4; ++ri) {
        const float4 tv = *(const float4*)(&tb[p][r0 + ri][jb * 4]);
        acc[ri][0] += tv.x * w0.x + tv.y * w1r.x + tv.z * w2r.x + tv.w * w3.x;
        acc[ri][1] += tv.x * w0.y + tv.y * w1r.y + tv.z * w2r.y + tv.w * w3.y;
        acc[ri][2] += tv.x * w0.z + tv.y * w1r.z + tv.z * w2r.z + tv.w * w3.z;
        acc[ri][3] += tv.x * w0.w + tv.y * w1r.w + tv.z * w2r.w + tv.w * w3.w;
      }
    }
    #pragma unroll
    for (int ri = 0; ri < 4; ++ri)
      #pragma unroll
      for (int ci = 0; ci < 4; ++ci) {
        const int cc = c + ci;
        const float v = acc[ri][ci] * scale;
        if (p == 0)      qb[r0 + ri][cc] = __float2bfloat16(v);
        else if (p == 1) kb[r0 + ri][cc] = __float2bfloat16(v);
        else             vb[cc][r0 + ri] = __float2bfloat16(v);
      }
  }
  __syncthreads();

  // ---- Q write ----
  for (int i = tid; i < 512; i += 256) {
    const int h  = i >> 6;
    const int r  = (i >> 3) & 7;
    const int d8 = i & 7;
    *(float4*)(Qg + ((size_t)b * SEQ + h * NSEQ + n0 + r) * DH + d8 * 8) =
        *(const float4*)(&qb[r][h * 64 + d8 * 8]);
  }

  // ---- K_sw write ----
  for (int i = tid; i < 512; i += 256) {
    const int h    = i >> 6;
    const int ks   = (i >> 5) & 1;
    const int quad = (i >> 3) & 3;
    const int r    = i & 7;
    const int lane = quad * 16 + (nb8 & 1) * 8 + r;
    const size_t dst = (size_t)b * KVSW_BATCH
        + ((size_t)((h * 64 + (nb8 >> 1)) * 2 + ks) * 64 + lane) * 8;
    *(float4*)(KSg + dst) = *(const float4*)(&kb[r][h * 64 + ks * 32 + quad * 8]);
  }

  // ---- V_sw write ----
  for (int i = tid; i < 1024; i += 256) {
    const int g   = i >> 9;
    const int d   = i & 511;
    const int h   = d >> 6;
    const int dnt = (d >> 4) & 3;
    const int dm  = d & 15;
    const int lane = ((nb8 * 2 + g) & 3) * 16 + dm;
    const size_t dst = (size_t)b * KVSW_BATCH
        + ((size_t)((h * 32 + (nb8 >> 2)) * 4 + dnt) * 64 + lane) * 8
        + ((nb8 >> 1) & 1) * 4;
    *(uint2*)(VSg + dst) = *(const uint2*)(&vb[d][g * 4]);
  }
}

// ---------------- kernel 2: attention, kv-split partial blocks (R8/R9) ----------------
struct PairBuf {
  bf16x8 k[2][2];   // [strip][k-span]
  bf16x8 v[4];      // [d-tile]
};

__global__ __launch_bounds__(256, 3) void attn_kernel(
    const __hip_bfloat16* __restrict__ Qg,
    const __hip_bfloat16* __restrict__ KSg,
    const __hip_bfloat16* __restrict__ VSg,
    float* __restrict__ OPg,       // [2][B_][SEQ][DH]
    float* __restrict__ PSg)       // [2][B_][SEQ]
{
  __shared__ float Osh[4][16][68];
  __shared__ float psums[4][64];

  const int tid  = threadIdx.x;
  const int wave = tid >> 6;
  const int lane = tid & 63;
  const int lrow = lane & 15;
  const int quad = lane >> 4;

  const int xcd   = blockIdx.x & 7;
  const int idx   = blockIdx.x >> 3;       // [0,128)
  const int b     = xcd >> 1;
  const int half  = idx & 1;
  const int qtile = (xcd & 1) * 64 + (idx >> 1);
  const int qbase = qtile * 64;

  const __hip_bfloat16* Qb  = Qg + ((size_t)b * SEQ + qbase) * DH;
  const __hip_bfloat16* kp0 = KSg + (size_t)b * KVSW_BATCH + half * 262144
                              + (size_t)wave * 65536 + lane * 8;
  const __hip_bfloat16* vp0 = VSg + (size_t)b * KVSW_BATCH + half * 262144
                              + (size_t)wave * 65536 + lane * 8;

  bf16x8 qf[4][2];
  #pragma unroll
  for (int mt = 0; mt < 4; ++mt)
    #pragma unroll
    for (int s = 0; s < 2; ++s)
      qf[mt][s] = *(const bf16x8*)(Qb + (mt * 16 + lrow) * DH + s * 32 + quad * 8);

  floatx4 oacc[4][4];   // [mt][dnt] — 64 acc regs (unified budget)
  #pragma unroll
  for (int mt = 0; mt < 4; ++mt)
    #pragma unroll
    for (int dnt = 0; dnt < 4; ++dnt)
      oacc[mt][dnt] = (floatx4){0.f, 0.f, 0.f, 0.f};
  float psum[4] = {0.f, 0.f, 0.f, 0.f};

  #pragma unroll 2
  for (int pair = 0; pair < 32; ++pair) {
    PairBuf pb;
    const __hip_bfloat16* kp = kp0 + pair * 2048;
    pb.k[0][0] = *(const bf16x8*)(kp);
    pb.k[0][1] = *(const bf16x8*)(kp + 512);
    pb.k[1][0] = *(const bf16x8*)(kp + 1024);
    pb.k[1][1] = *(const bf16x8*)(kp + 1536);
    const __hip_bfloat16* vp = vp0 + pair * 2048;
    #pragma unroll
    for (int dnt = 0; dnt < 4; ++dnt)
      pb.v[dnt] = *(const bf16x8*)(vp + dnt * 512);

    #pragma unroll
    for (int mt = 0; mt < 4; ++mt) {
      floatx4 s0 = (floatx4){0.f, 0.f, 0.f, 0.f};
      floatx4 s1 = (floatx4){0.f, 0.f, 0.f, 0.f};
      s0 = __builtin_amdgcn_mfma_f32_16x16x32_bf16(pb.k[0][0], qf[mt][0], s0, 0, 0, 0);
      s0 = __builtin_amdgcn_mfma_f32_16x16x32_bf16(pb.k[0][1], qf[mt][1], s0, 0, 0, 0);
      s1 = __builtin_amdgcn_mfma_f32_16x16x32_bf16(pb.k[1][0], qf[mt][0], s1, 0, 0, 0);
      s1 = __builtin_amdgcn_mfma_f32_16x16x32_bf16(pb.k[1][1], qf[mt][1], s1, 0, 0, 0);
      float p[8];
      #pragma unroll
      for (int r = 0; r < 4; ++r) {
        p[r]     = __builtin_amdgcn_exp2f(s0[r]);
        p[4 + r] = __builtin_amdgcn_exp2f(s1[r]);
      }
      psum[mt] += ((p[0] + p[1]) + (p[2] + p[3])) + ((p[4] + p[5]) + (p[6] + p[7]));
      bf16x8 pa;
      #pragma unroll
      for (int j = 0; j < 8; ++j) pa[j] = (__bf16)p[j];
      #pragma unroll
      for (int dnt = 0; dnt < 4; ++dnt)
        oacc[mt][dnt] = __builtin_amdgcn_mfma_f32_16x16x32_bf16(pa, pb.v[dnt], oacc[mt][dnt], 0, 0, 0);
    }
  }

  #pragma unroll
  for (int mt = 0; mt < 4; ++mt) {
    float s = psum[mt];
    s += __shfl_xor(s, 16, 64);
    s += __shfl_xor(s, 32, 64);
    psum[mt] = s;
  }
  if (quad == 0) {
    #pragma unroll
    for (int mt = 0; mt < 4; ++mt)
      psums[wave][mt * 16 + lrow] = psum[mt];
  }

  const size_t opbase = ((size_t)half * B_ + b) * SEQ + qbase;

  #pragma unroll
  for (int mt = 0; mt < 4; ++mt) {
    #pragma unroll
    for (int dnt = 0; dnt < 4; ++dnt)
      #pragma unroll
      for (int r = 0; r < 4; ++r)
        Osh[wave][quad * 4 + r][dnt * 16 + lrow] = oacc[mt][dnt][r];
    __syncthreads();

    {
      const int q16 = tid >> 4;
      const int d0  = (tid & 15) * 4;
      float4 a0 = *(const float4*)(&Osh[0][q16][d0]);
      float4 a1 = *(const float4*)(&Osh[1][q16][d0]);
      float4 a2 = *(const float4*)(&Osh[2][q16][d0]);
      float4 a3 = *(const float4*)(&Osh[3][q16][d0]);
      float4 res;
      res.x = (a0.x + a1.x) + (a2.x + a3.x);
      res.y = (a0.y + a1.y) + (a2.y + a3.y);
      res.z = (a0.z + a1.z) + (a2.z + a3.z);
      res.w = (a0.w + a1.w) + (a2.w + a3.w);
      *(float4*)(OPg + (opbase + mt * 16 + q16) * DH + d0) = res;
    }
    if (mt == 0 && tid < 64) {
      const float tot = (psums[0][tid] + psums[1][tid]) + (psums[2][tid] + psums[3][tid]);
      PSg[opbase + tid] = tot;
    }
    __syncthreads();
  }
}

// ---------------- kernel 3: out = merge(Opart)/denom @ wo + bo ----------------
// R10 rewrite. grid 256 (1 block/CU): 16 rows x 256 cols per block.
// Thread = 4 rows x 4 cols; wo rows ping-pong prefetched in registers;
// os reads are wave-broadcast (all lanes of a wave share the row-group).
__global__ __launch_bounds__(256) void out_kernel(
    const float* __restrict__ OPg, const float* __restrict__ PSg,
    const float* __restrict__ wo, const float* __restrict__ bo,
    float* __restrict__ out)
{
  const int tid = threadIdx.x;
  const int b   = blockIdx.x >> 6;
  const int n0  = (blockIdx.x & 63) << 4;

  __shared__ __align__(16) float os[16][516];   // pad 516: row stride not bank-aligned
  __shared__ float invs[16][8];

  if (tid < 128) {
    const int r = tid >> 3, h = tid & 7;
    const size_t row = (size_t)b * SEQ + h * NSEQ + n0 + r;
    invs[r][h] = 1.0f / (PSg[row] + PSg[(size_t)B_ * SEQ + row]);
  }
  __syncthreads();

  // gather + merge halves + normalize (float4 over K dim)
  for (int i = tid; i < 2048; i += 256) {
    const int r  = i >> 7;
    const int c4 = (i & 127) * 4;          // cc = h*64+d, d%4==0
    const int h  = c4 >> 6;
    const size_t idx = ((size_t)b * SEQ + h * NSEQ + n0 + r) * DH + (c4 & 63);
    const float4 p0 = *(const float4*)(OPg + idx);
    const float4 p1 = *(const float4*)(OPg + (size_t)B_ * SEQ * DH + idx);
    const float inv = invs[r][h];
    float4 m;
    m.x = (p0.x + p1.x) * inv;
    m.y = (p0.y + p1.y) * inv;
    m.z = (p0.z + p1.z) * inv;
    m.w = (p0.w + p1.w) * inv;
    *(float4*)(&os[r][c4]) = m;
  }
  __syncthreads();

  const int oq = tid & 63;                 // col group: o = oq*4
  const int rq = tid >> 6;                 // row group: rows rq*4..rq*4+3
  const int o  = oq * 4;
  const int r0 = rq * 4;

  float acc[4][4];
  #pragma unroll
  for (int i = 0; i < 4; ++i)
    #pragma unroll
    for (int j = 0; j < 4; ++j) acc[i][j] = 0.f;

  // ping-pong prefetch of wo rows (4 float4 in flight)
  float4 wa0 = *(const float4*)(wo + 0 * QS + o);
  float4 wa1 = *(const float4*)(wo + 1 * QS + o);
  float4 wa2 = *(const float4*)(wo + 2 * QS + o);
  float4 wa3 = *(const float4*)(wo + 3 * QS + o);

  for (int jb = 0; jb < 128; ++jb) {
    const int jn = (jb < 127) ? jb + 1 : 127;
    float4 wb0 = *(const float4*)(wo + (jn * 4 + 0) * QS + o);
    float4 wb1 = *(const float4*)(wo + (jn * 4 + 1) * QS + o);
    float4 wb2 = *(const float4*)(wo + (jn * 4 + 2) * QS + o);
    float4 wb3 = *(const float4*)(wo + (jn * 4 + 3) * QS + o);

    #pragma unroll
    for (int ri = 0; ri < 4; ++ri) {
      const float4 ov = *(const float4*)(&os[r0 + ri][jb * 4]);   // wave-broadcast
      acc[ri][0] += ov.x * wa0.x + ov.y * wa1.x + ov.z * wa2.x + ov.w * wa3.x;
      acc[ri][1] += ov.x * wa0.y + ov.y * wa1.y + ov.z * wa2.y + ov.w * wa3.y;
      acc[ri][2] += ov.x * wa0.z + ov.y * wa1.z + ov.z * wa2.z + ov.w * wa3.z;
      acc[ri][3] += ov.x * wa0.w + ov.y * wa1.w + ov.z * wa2.w + ov.w * wa3.w;
    }
    wa0 = wb0; wa1 = wb1; wa2 = wb2; wa3 = wb3;
  }

  const float4 bv = *(const float4*)(bo + o);
  #pragma unroll
  for (int ri = 0; ri < 4; ++ri) {
    float4 res;
    res.x = acc[ri][0] + bv.x;
    res.y = acc[ri][1] + bv.y;
    res.z = acc[ri][2] + bv.z;
    res.w = acc[ri][3] + bv.w;
    *(float4*)(out + ((size_t)b * NSEQ + n0 + r0 + ri) * QS + o) = res;
  }
}

extern "C" void kernel_launch(void* const* d_in, const int* in_sizes, int n_in,
                              void* d_out, int out_size, void* d_ws, size_t ws_size,
                              hipStream_t stream) {
  const float* x   = (const float*)d_in[0];
  const float* wq1 = (const float*)d_in[1];
  const float* wq2 = (const float*)d_in[2];
  const float* wk1 = (const float*)d_in[3];
  const float* wk2 = (const float*)d_in[4];
  const float* wv1 = (const float*)d_in[5];
  const float* wv2 = (const float*)d_in[6];
  const float* wo  = (const float*)d_in[7];
  const float* bo  = (const float*)d_in[8];
  float* out = (float*)d_out;

  __hip_bfloat16* Qg  = (__hip_bfloat16*)d_ws;
  __hip_bfloat16* KSg = Qg + (size_t)B_ * SEQ * DH;
  __hip_bfloat16* VSg = KSg + (size_t)B_ * KVSW_BATCH;
  float*          OPg = (float*)(VSg + (size_t)B_ * KVSW_BATCH);   // [2][B_][SEQ][DH]
  float*          PSg = OPg + 2 * (size_t)B_ * SEQ * DH;           // [2][B_][SEQ]

  qkv_kernel<<<512, 256, 0, stream>>>(x, wq1, wq2, wk1, wk2, wv1, wv2, Qg, KSg, VSg);
  attn_kernel<<<1024, 256, 0, stream>>>(Qg, KSg, VSg, OPg, PSg);
  out_kernel<<<256, 256, 0, stream>>>(OPg, PSg, wo, bo, out);
}